// Round 4
// baseline (1729.262 us; speedup 1.0000x reference)
//
#include <hip/hip_runtime.h>
#include <math.h>

#define SS 2048
#define DD 1024
#define HH 16
#define CAPC 65536u   // candidate slots per head (expected ~3K)

// quantile index: floor(0.95*(S*S-1)) = floor(3984587.85)
#define K_A 3984587u
#define K_B 3984588u
#define QFRAC 0.85f

__device__ __forceinline__ unsigned sortkey(float f) {
  unsigned b = __float_as_uint(f);
  return (b & 0x80000000u) ? ~b : (b | 0x80000000u);
}
__device__ __forceinline__ float inv_sortkey(unsigned u) {
  unsigned b = (u & 0x80000000u) ? (u ^ 0x80000000u) : ~u;
  return __uint_as_float(b);
}

// ---------------- fp32 GEMM: C[2048,1024] = A[2048,1024] @ B[1024,1024] + bias ----------------
// 64x64 tile, 256 threads, 4x4 per thread. Grid (N/64, M/64[, z]).
// 64-tile (not 128): grid 1536 blocks = 6 blocks/CU -> 24 waves/CU; 128-tile gave 1.5/CU (14.6% occ).
__device__ __forceinline__ void gemm64(const float* __restrict__ A,
                                       const float* __restrict__ B,
                                       const float* __restrict__ bias,
                                       float* __restrict__ C,
                                       int bm, int bn)
{
  __shared__ float As[16][68];   // +4 pad: store conflicts 4-way -> 2-way (free)
  __shared__ float Bs[16][68];
  const int t  = threadIdx.x;
  const int tx = t & 15, ty = t >> 4;
  const int m0 = bm * 64, n0 = bn * 64;

  float acc[4][4];
#pragma unroll
  for (int i = 0; i < 4; ++i)
#pragma unroll
    for (int j = 0; j < 4; ++j) acc[i][j] = 0.f;

  const int ar = t >> 2;          // A row 0..63
  const int ak = (t & 3) * 4;     // A col group
  const int br = t >> 4;          // B row 0..15
  const int bc = (t & 15) * 4;    // B col group

  for (int kb = 0; kb < 1024; kb += 16) {
    float4 a0 = *(const float4*)&A[(size_t)(m0 + ar) * 1024 + kb + ak];
    float4 b0 = *(const float4*)&B[(size_t)(kb + br) * 1024 + n0 + bc];
    __syncthreads();  // previous iter's LDS reads done before overwrite
    As[ak+0][ar] = a0.x; As[ak+1][ar] = a0.y; As[ak+2][ar] = a0.z; As[ak+3][ar] = a0.w;
    *(float4*)&Bs[br][bc] = b0;
    __syncthreads();
#pragma unroll
    for (int k = 0; k < 16; ++k) {
      float4 av = *(const float4*)&As[k][ty*4];
      float4 bv = *(const float4*)&Bs[k][tx*4];
      acc[0][0] = fmaf(av.x, bv.x, acc[0][0]); acc[0][1] = fmaf(av.x, bv.y, acc[0][1]);
      acc[0][2] = fmaf(av.x, bv.z, acc[0][2]); acc[0][3] = fmaf(av.x, bv.w, acc[0][3]);
      acc[1][0] = fmaf(av.y, bv.x, acc[1][0]); acc[1][1] = fmaf(av.y, bv.y, acc[1][1]);
      acc[1][2] = fmaf(av.y, bv.z, acc[1][2]); acc[1][3] = fmaf(av.y, bv.w, acc[1][3]);
      acc[2][0] = fmaf(av.z, bv.x, acc[2][0]); acc[2][1] = fmaf(av.z, bv.y, acc[2][1]);
      acc[2][2] = fmaf(av.z, bv.z, acc[2][2]); acc[2][3] = fmaf(av.z, bv.w, acc[2][3]);
      acc[3][0] = fmaf(av.w, bv.x, acc[3][0]); acc[3][1] = fmaf(av.w, bv.y, acc[3][1]);
      acc[3][2] = fmaf(av.w, bv.z, acc[3][2]); acc[3][3] = fmaf(av.w, bv.w, acc[3][3]);
    }
  }
#pragma unroll
  for (int i = 0; i < 4; ++i) {
    const int row = m0 + ty*4 + i;
    const int col = n0 + tx*4;
    float4 o;
    o.x = acc[i][0] + bias[col+0];
    o.y = acc[i][1] + bias[col+1];
    o.z = acc[i][2] + bias[col+2];
    o.w = acc[i][3] + bias[col+3];
    *(float4*)&C[(size_t)row * 1024 + col] = o;
  }
}

__global__ __launch_bounds__(256) void gemm_qkv(const float* __restrict__ x,
    const float* __restrict__ Wq, const float* __restrict__ bq,
    const float* __restrict__ Wk, const float* __restrict__ bk,
    const float* __restrict__ Wv, const float* __restrict__ bv,
    float* __restrict__ Q, float* __restrict__ K, float* __restrict__ V)
{
  const int z = blockIdx.z;
  const float* W = (z == 0) ? Wq : (z == 1) ? Wk : Wv;
  const float* b = (z == 0) ? bq : (z == 1) ? bk : bv;
  float*       O = (z == 0) ? Q  : (z == 1) ? K  : V;
  gemm64(x, W, b, O, blockIdx.y, blockIdx.x);
}

__global__ __launch_bounds__(256) void gemm_single(const float* __restrict__ A,
    const float* __restrict__ W, const float* __restrict__ b, float* __restrict__ O)
{
  gemm64(A, W, b, O, blockIdx.y, blockIdx.x);
}

// ---------------- scores[hh][i][j] = (Q_h[i,:] . K_h[j,:]) / 8 ----------------
__global__ __launch_bounds__(256) void scores_kernel(const float* __restrict__ Q,
                                                     const float* __restrict__ Km,
                                                     float* __restrict__ scores,
                                                     int h0)
{
  const int bn = blockIdx.x, bm = blockIdx.y, hh = blockIdx.z;
  const int h = h0 + hh;
  __shared__ float Qs[64][128];
  __shared__ float Ks[64][128];
  const int t  = threadIdx.x;
  const int tx = t & 15, ty = t >> 4;
  const int m0 = bm * 128, n0 = bn * 128;

  const int r   = t >> 1;          // 0..127
  const int kb0 = (t & 1) * 32;    // 0 or 32
#pragma unroll
  for (int f = 0; f < 8; ++f) {
    const int kc = kb0 + f*4;
    float4 q = *(const float4*)&Q [(size_t)(m0 + r) * 1024 + h*64 + kc];
    Qs[kc+0][r] = q.x; Qs[kc+1][r] = q.y; Qs[kc+2][r] = q.z; Qs[kc+3][r] = q.w;
    float4 k = *(const float4*)&Km[(size_t)(n0 + r) * 1024 + h*64 + kc];
    Ks[kc+0][r] = k.x; Ks[kc+1][r] = k.y; Ks[kc+2][r] = k.z; Ks[kc+3][r] = k.w;
  }
  __syncthreads();

  float acc[8][8];
#pragma unroll
  for (int i = 0; i < 8; ++i)
#pragma unroll
    for (int j = 0; j < 8; ++j) acc[i][j] = 0.f;

  for (int k = 0; k < 64; ++k) {
    float av[8], bv[8];
    *(float4*)&av[0] = *(const float4*)&Qs[k][ty*8];
    *(float4*)&av[4] = *(const float4*)&Qs[k][ty*8 + 4];
    *(float4*)&bv[0] = *(const float4*)&Ks[k][tx*8];
    *(float4*)&bv[4] = *(const float4*)&Ks[k][tx*8 + 4];
#pragma unroll
    for (int i = 0; i < 8; ++i)
#pragma unroll
      for (int j = 0; j < 8; ++j)
        acc[i][j] = fmaf(av[i], bv[j], acc[i][j]);
  }

#pragma unroll
  for (int i = 0; i < 8; ++i) {
    const int row = m0 + ty*8 + i;
#pragma unroll
    for (int j4 = 0; j4 < 2; ++j4) {
      const int col = n0 + tx*8 + j4*4;
      float4 o;
      o.x = acc[i][j4*4+0] * 0.125f;
      o.y = acc[i][j4*4+1] * 0.125f;
      o.z = acc[i][j4*4+2] * 0.125f;
      o.w = acc[i][j4*4+3] * 0.125f;
      *(float4*)&scores[((size_t)hh * SS + row) * SS + col] = o;
    }
  }
}

// ---------------- radix select (exact quantile) ----------------
__global__ __launch_bounds__(256) void init_state(unsigned* __restrict__ state,
                                                  unsigned* __restrict__ hist,
                                                  unsigned* __restrict__ ccnt, int cnt)
{
  const int t = threadIdx.x;
  for (int i = t; i < HH * 512; i += 256) hist[i] = 0;   // full clear, cnt-independent
  if (t < HH) ccnt[t] = 0;
  if (t < cnt) {
    state[t*4+0] = 0u; state[t*4+1] = K_A;
    state[t*4+2] = 0u; state[t*4+3] = K_B;
  }
}

__global__ __launch_bounds__(256) void hist_pass(const float* __restrict__ scores,
                                                 unsigned* __restrict__ hist,
                                                 const unsigned* __restrict__ state,
                                                 int shift, unsigned himask)
{
  const int hh = blockIdx.y;
  __shared__ unsigned lh0[256], lh1[256];
  const int t = threadIdx.x;
  lh0[t] = 0; lh1[t] = 0;
  __syncthreads();
  const unsigned prefA = state[hh*4+0];
  const unsigned prefB = state[hh*4+2];
  const float4* base = (const float4*)(scores + (size_t)hh * SS * SS)
                       + (size_t)blockIdx.x * 16384;
  for (int i = t; i < 16384; i += 256) {
    float4 v = base[i];
    unsigned u;
    u = sortkey(v.x);
    if ((u & himask) == prefA) atomicAdd(&lh0[(u >> shift) & 255], 1u);
    if ((u & himask) == prefB) atomicAdd(&lh1[(u >> shift) & 255], 1u);
    u = sortkey(v.y);
    if ((u & himask) == prefA) atomicAdd(&lh0[(u >> shift) & 255], 1u);
    if ((u & himask) == prefB) atomicAdd(&lh1[(u >> shift) & 255], 1u);
    u = sortkey(v.z);
    if ((u & himask) == prefA) atomicAdd(&lh0[(u >> shift) & 255], 1u);
    if ((u & himask) == prefB) atomicAdd(&lh1[(u >> shift) & 255], 1u);
    u = sortkey(v.w);
    if ((u & himask) == prefA) atomicAdd(&lh0[(u >> shift) & 255], 1u);
    if ((u & himask) == prefB) atomicAdd(&lh1[(u >> shift) & 255], 1u);
  }
  __syncthreads();
  if (lh0[t]) atomicAdd(&hist[(hh*2 + 0)*256 + t], lh0[t]);
  if (lh1[t]) atomicAdd(&hist[(hh*2 + 1)*256 + t], lh1[t]);
}

// pass 2: histogram bits 15..8 under 16-bit prefix AND compact matching sortkeys.
// Candidates ~3K/head (prefix width ~2^-8 relative); CAP=64K gives 20x margin.
__global__ __launch_bounds__(256) void hist_compact(const float* __restrict__ scores,
                                                    unsigned* __restrict__ hist,
                                                    const unsigned* __restrict__ state,
                                                    unsigned* __restrict__ cand,
                                                    unsigned* __restrict__ ccnt)
{
  const int hh = blockIdx.y;
  __shared__ unsigned lh0[256], lh1[256];
  const int t = threadIdx.x;
  lh0[t] = 0; lh1[t] = 0;
  __syncthreads();
  const unsigned prefA = state[hh*4+0];
  const unsigned prefB = state[hh*4+2];
  unsigned* __restrict__ mycand = cand + (size_t)hh * CAPC;
  const float4* base = (const float4*)(scores + (size_t)hh * SS * SS)
                       + (size_t)blockIdx.x * 16384;
  for (int i = t; i < 16384; i += 256) {
    float4 v = base[i];
    unsigned u; bool a, b;
    u = sortkey(v.x);
    a = ((u & 0xFFFF0000u) == prefA); b = ((u & 0xFFFF0000u) == prefB);
    if (a) atomicAdd(&lh0[(u >> 8) & 255], 1u);
    if (b) atomicAdd(&lh1[(u >> 8) & 255], 1u);
    if (a | b) { unsigned id = atomicAdd(&ccnt[hh], 1u); if (id < CAPC) mycand[id] = u; }
    u = sortkey(v.y);
    a = ((u & 0xFFFF0000u) == prefA); b = ((u & 0xFFFF0000u) == prefB);
    if (a) atomicAdd(&lh0[(u >> 8) & 255], 1u);
    if (b) atomicAdd(&lh1[(u >> 8) & 255], 1u);
    if (a | b) { unsigned id = atomicAdd(&ccnt[hh], 1u); if (id < CAPC) mycand[id] = u; }
    u = sortkey(v.z);
    a = ((u & 0xFFFF0000u) == prefA); b = ((u & 0xFFFF0000u) == prefB);
    if (a) atomicAdd(&lh0[(u >> 8) & 255], 1u);
    if (b) atomicAdd(&lh1[(u >> 8) & 255], 1u);
    if (a | b) { unsigned id = atomicAdd(&ccnt[hh], 1u); if (id < CAPC) mycand[id] = u; }
    u = sortkey(v.w);
    a = ((u & 0xFFFF0000u) == prefA); b = ((u & 0xFFFF0000u) == prefB);
    if (a) atomicAdd(&lh0[(u >> 8) & 255], 1u);
    if (b) atomicAdd(&lh1[(u >> 8) & 255], 1u);
    if (a | b) { unsigned id = atomicAdd(&ccnt[hh], 1u); if (id < CAPC) mycand[id] = u; }
  }
  __syncthreads();
  if (lh0[t]) atomicAdd(&hist[(hh*2 + 0)*256 + t], lh0[t]);
  if (lh1[t]) atomicAdd(&hist[(hh*2 + 1)*256 + t], lh1[t]);
}

__global__ __launch_bounds__(256) void scan_pass(unsigned* __restrict__ hist,
                                                 unsigned* __restrict__ state,
                                                 float* __restrict__ thr,
                                                 int shift, int cnt)
{
  const int t = threadIdx.x;
  if (t < cnt) {
    float vals[2];
    for (int tgt = 0; tgt < 2; ++tgt) {
      unsigned pref = state[t*4 + tgt*2];
      unsigned k    = state[t*4 + tgt*2 + 1];
      unsigned cum = 0; int b = 0;
      for (; b < 256; ++b) {
        unsigned c = hist[(t*2 + tgt)*256 + b];
        if (cum + c > k) break;
        cum += c;
      }
      if (b == 256) b = 255;  // defensive
      pref |= ((unsigned)b) << shift;
      k -= cum;
      state[t*4 + tgt*2]     = pref;
      state[t*4 + tgt*2 + 1] = k;
      if (shift == 0) vals[tgt] = inv_sortkey(pref);
    }
    if (shift == 0) thr[t] = vals[0] + QFRAC * (vals[1] - vals[0]);
  }
  __syncthreads();
  for (int i = t; i < HH * 512; i += 256) hist[i] = 0;  // full clear for next pass
}

// last 8-bit digit from the candidate list (replaces a full 268 MB pass)
__global__ __launch_bounds__(256) void final_select(const unsigned* __restrict__ cand,
                                                    const unsigned* __restrict__ ccnt,
                                                    const unsigned* __restrict__ state,
                                                    float* __restrict__ thr)
{
  const int hh = blockIdx.x;
  const int t = threadIdx.x;
  __shared__ unsigned h0[256], h1[256];
  h0[t] = 0; h1[t] = 0;
  __syncthreads();
  const unsigned prefA = state[hh*4+0], kA = state[hh*4+1];
  const unsigned prefB = state[hh*4+2], kB = state[hh*4+3];
  unsigned n = ccnt[hh]; if (n > CAPC) n = CAPC;
  const unsigned* __restrict__ list = cand + (size_t)hh * CAPC;
  for (unsigned i = t; i < n; i += 256) {
    unsigned u = list[i];
    if ((u & 0xFFFFFF00u) == prefA) atomicAdd(&h0[u & 255], 1u);
    if ((u & 0xFFFFFF00u) == prefB) atomicAdd(&h1[u & 255], 1u);
  }
  __syncthreads();
  if (t == 0) {
    unsigned cum = 0; int b = 0;
    for (; b < 256; ++b) { unsigned c = h0[b]; if (cum + c > kA) break; cum += c; }
    if (b == 256) b = 255;
    const float vA = inv_sortkey(prefA | (unsigned)b);
    cum = 0; int b2 = 0;
    for (; b2 < 256; ++b2) { unsigned c = h1[b2]; if (cum + c > kB) break; cum += c; }
    if (b2 == 256) b2 = 255;
    const float vB = inv_sortkey(prefB | (unsigned)b2);
    thr[hh] = vA + QFRAC * (vB - vA);
  }
}

// ---------------- wave-per-row masked softmax + ballot-compacted sparse PV ----------------
__global__ __launch_bounds__(256) void softmax_pv2(const float* __restrict__ scores,
                                                   const float* __restrict__ thrArr,
                                                   const float* __restrict__ V,
                                                   float* __restrict__ ctx,
                                                   int h0)
{
  const int wave = threadIdx.x >> 6;
  const int lane = threadIdx.x & 63;
  const int row  = blockIdx.x * 4 + wave;
  const int hh   = blockIdx.y;
  const int h    = h0 + hh;
  const float thr = thrArr[hh];
  const float* __restrict__ srow = scores + ((size_t)hh * SS + row) * SS;

  float p[32];
#pragma unroll
  for (int t = 0; t < 32; ++t) p[t] = srow[t*64 + lane];

  float m = -INFINITY;
#pragma unroll
  for (int t = 0; t < 32; ++t)
    if (p[t] >= thr) m = fmaxf(m, p[t]);
#pragma unroll
  for (int off = 32; off; off >>= 1) m = fmaxf(m, __shfl_xor(m, off));

  float sum = 0.f;
#pragma unroll
  for (int t = 0; t < 32; ++t) {
    float e = (p[t] >= thr) ? __expf(p[t] - m) : 0.f;
    p[t] = e;
    sum += e;
  }
#pragma unroll
  for (int off = 32; off; off >>= 1) sum += __shfl_xor(sum, off);

  float acc0 = 0.f, acc1 = 0.f;
  const float* __restrict__ vcol = V + h*64 + lane;
#pragma unroll
  for (int t = 0; t < 32; ++t) {
    unsigned long long mk = __ballot(p[t] != 0.f);
    const float* __restrict__ vt = vcol + (size_t)t * 64 * 1024;
    while (mk) {
      int b0 = __ffsll(mk) - 1; mk &= mk - 1;
      if (mk) {
        int b1 = __ffsll(mk) - 1; mk &= mk - 1;
        float va = vt[(size_t)b0 * 1024];
        float vb = vt[(size_t)b1 * 1024];
        acc0 = fmaf(__shfl(p[t], b0), va, acc0);
        acc1 = fmaf(__shfl(p[t], b1), vb, acc1);
      } else {
        acc0 = fmaf(__shfl(p[t], b0), vt[(size_t)b0 * 1024], acc0);
      }
    }
  }
  ctx[(size_t)row * 1024 + h*64 + lane] = (acc0 + acc1) / sum;
}

// ---------------- host ----------------
extern "C" void kernel_launch(void* const* d_in, const int* in_sizes, int n_in,
                              void* d_out, int out_size, void* d_ws, size_t ws_size,
                              hipStream_t stream)
{
  const float* x  = (const float*)d_in[0];
  const float* Wq = (const float*)d_in[1];
  const float* bq = (const float*)d_in[2];
  const float* Wk = (const float*)d_in[3];
  const float* bk = (const float*)d_in[4];
  const float* Wv = (const float*)d_in[5];
  const float* bv = (const float*)d_in[6];
  const float* Wo = (const float*)d_in[7];
  const float* bo = (const float*)d_in[8];
  float* out = (float*)d_out;
  char*  ws  = (char*)d_ws;

  const size_t SD = (size_t)SS * DD * sizeof(float);  // 8 MiB
  float*    Q     = (float*)(ws + 0*SD);
  float*    K     = (float*)(ws + 1*SD);
  float*    V     = (float*)(ws + 2*SD);
  float*    ctx   = (float*)(ws + 3*SD);
  unsigned* state = (unsigned*)(ws + 4*SD);
  float*    thr   = (float*)(ws + 4*SD + 4096);
  unsigned* ccnt  = (unsigned*)(ws + 4*SD + 8192);
  unsigned* hist  = (unsigned*)(ws + 4*SD + 16384);    // 32 KiB
  unsigned* cand  = (unsigned*)(ws + 4*SD + 65536);    // HH * CAPC * 4 = 4 MiB
  const size_t off_scores = 4*SD + 65536 + (size_t)HH * CAPC * 4;
  float* scores = (float*)(ws + off_scores);
  const size_t perHead = (size_t)SS * SS * sizeof(float);  // 16 MiB

  int CH = 1;
  if (ws_size > off_scores + perHead)
    CH = (int)((ws_size - off_scores) / perHead);
  if (CH > HH) CH = HH;
  if (CH < 1)  CH = 1;

  gemm_qkv<<<dim3(16, 32, 3), 256, 0, stream>>>(x, Wq, bq, Wk, bk, Wv, bv, Q, K, V);

  for (int h0 = 0; h0 < HH; h0 += CH) {
    const int cnt = (HH - h0 < CH) ? (HH - h0) : CH;
    scores_kernel<<<dim3(16, 16, cnt), 256, 0, stream>>>(Q, K, scores, h0);
    init_state<<<1, 256, 0, stream>>>(state, hist, ccnt, cnt);
    // pass 0: bits 31..24 (full read)
    hist_pass<<<dim3(64, cnt), 256, 0, stream>>>(scores, hist, state, 24, 0u);
    scan_pass<<<1, 256, 0, stream>>>(hist, state, thr, 24, cnt);
    // pass 1: bits 23..16 (full read)
    hist_pass<<<dim3(64, cnt), 256, 0, stream>>>(scores, hist, state, 16, 0xFF000000u);
    scan_pass<<<1, 256, 0, stream>>>(hist, state, thr, 16, cnt);
    // pass 2: bits 15..8 (full read) + candidate compaction
    hist_compact<<<dim3(64, cnt), 256, 0, stream>>>(scores, hist, state, cand, ccnt);
    scan_pass<<<1, 256, 0, stream>>>(hist, state, thr, 8, cnt);
    // pass 3: bits 7..0 from candidate list only
    final_select<<<cnt, 256, 0, stream>>>(cand, ccnt, state, thr);
    softmax_pv2<<<dim3(SS/4, cnt), 256, 0, stream>>>(scores, thr, V, ctx, h0);
  }

  gemm_single<<<dim3(16, 32), 256, 0, stream>>>(ctx, Wo, bo, out);
}

// Round 5
// 1074.462 us; speedup vs baseline: 1.6094x; 1.6094x over previous
//
#include <hip/hip_runtime.h>
#include <math.h>

#define SS 2048
#define DD 1024
#define HH 16
#define CAPC 65536u   // candidate slots per head (expected ~5K)
#define LCAP 2048     // per-block LDS candidate buffer (expected ~80/block)

// quantile index: floor(0.95*(S*S-1)) = floor(3984587.85)
#define K_A 3984587u
#define K_B 3984588u
#define QFRAC 0.85f

__device__ __forceinline__ unsigned sortkey(float f) {
  unsigned b = __float_as_uint(f);
  return (b & 0x80000000u) ? ~b : (b | 0x80000000u);
}
__device__ __forceinline__ float inv_sortkey(unsigned u) {
  unsigned b = (u & 0x80000000u) ? (u ^ 0x80000000u) : ~u;
  return __uint_as_float(b);
}

// ---------------- fp32 GEMM: C[2048,1024] = A[2048,1024] @ B[1024,1024] + bias ----------------
// 64x64 tile, 256 threads, 4x4 per thread. Grid (N/64, M/64[, z]).
__device__ __forceinline__ void gemm64(const float* __restrict__ A,
                                       const float* __restrict__ B,
                                       const float* __restrict__ bias,
                                       float* __restrict__ C,
                                       int bm, int bn)
{
  __shared__ float As[16][68];   // +4 pad: store conflicts 4-way -> 2-way (free)
  __shared__ float Bs[16][68];
  const int t  = threadIdx.x;
  const int tx = t & 15, ty = t >> 4;
  const int m0 = bm * 64, n0 = bn * 64;

  float acc[4][4];
#pragma unroll
  for (int i = 0; i < 4; ++i)
#pragma unroll
    for (int j = 0; j < 4; ++j) acc[i][j] = 0.f;

  const int ar = t >> 2;          // A row 0..63
  const int ak = (t & 3) * 4;     // A col group
  const int br = t >> 4;          // B row 0..15
  const int bc = (t & 15) * 4;    // B col group

  for (int kb = 0; kb < 1024; kb += 16) {
    float4 a0 = *(const float4*)&A[(size_t)(m0 + ar) * 1024 + kb + ak];
    float4 b0 = *(const float4*)&B[(size_t)(kb + br) * 1024 + n0 + bc];
    __syncthreads();  // previous iter's LDS reads done before overwrite
    As[ak+0][ar] = a0.x; As[ak+1][ar] = a0.y; As[ak+2][ar] = a0.z; As[ak+3][ar] = a0.w;
    *(float4*)&Bs[br][bc] = b0;
    __syncthreads();
#pragma unroll
    for (int k = 0; k < 16; ++k) {
      float4 av = *(const float4*)&As[k][ty*4];
      float4 bv = *(const float4*)&Bs[k][tx*4];
      acc[0][0] = fmaf(av.x, bv.x, acc[0][0]); acc[0][1] = fmaf(av.x, bv.y, acc[0][1]);
      acc[0][2] = fmaf(av.x, bv.z, acc[0][2]); acc[0][3] = fmaf(av.x, bv.w, acc[0][3]);
      acc[1][0] = fmaf(av.y, bv.x, acc[1][0]); acc[1][1] = fmaf(av.y, bv.y, acc[1][1]);
      acc[1][2] = fmaf(av.y, bv.z, acc[1][2]); acc[1][3] = fmaf(av.y, bv.w, acc[1][3]);
      acc[2][0] = fmaf(av.z, bv.x, acc[2][0]); acc[2][1] = fmaf(av.z, bv.y, acc[2][1]);
      acc[2][2] = fmaf(av.z, bv.z, acc[2][2]); acc[2][3] = fmaf(av.z, bv.w, acc[2][3]);
      acc[3][0] = fmaf(av.w, bv.x, acc[3][0]); acc[3][1] = fmaf(av.w, bv.y, acc[3][1]);
      acc[3][2] = fmaf(av.w, bv.z, acc[3][2]); acc[3][3] = fmaf(av.w, bv.w, acc[3][3]);
    }
  }
#pragma unroll
  for (int i = 0; i < 4; ++i) {
    const int row = m0 + ty*4 + i;
    const int col = n0 + tx*4;
    float4 o;
    o.x = acc[i][0] + bias[col+0];
    o.y = acc[i][1] + bias[col+1];
    o.z = acc[i][2] + bias[col+2];
    o.w = acc[i][3] + bias[col+3];
    *(float4*)&C[(size_t)row * 1024 + col] = o;
  }
}

__global__ __launch_bounds__(256) void gemm_qkv(const float* __restrict__ x,
    const float* __restrict__ Wq, const float* __restrict__ bq,
    const float* __restrict__ Wk, const float* __restrict__ bk,
    const float* __restrict__ Wv, const float* __restrict__ bv,
    float* __restrict__ Q, float* __restrict__ K, float* __restrict__ V)
{
  const int z = blockIdx.z;
  const float* W = (z == 0) ? Wq : (z == 1) ? Wk : Wv;
  const float* b = (z == 0) ? bq : (z == 1) ? bk : bv;
  float*       O = (z == 0) ? Q  : (z == 1) ? K  : V;
  gemm64(x, W, b, O, blockIdx.y, blockIdx.x);
}

__global__ __launch_bounds__(256) void gemm_single(const float* __restrict__ A,
    const float* __restrict__ W, const float* __restrict__ b, float* __restrict__ O)
{
  gemm64(A, W, b, O, blockIdx.y, blockIdx.x);
}

// ---------------- scores[hh][i][j] = (Q_h[i,:] . K_h[j,:]) / 8 ----------------
__global__ __launch_bounds__(256) void scores_kernel(const float* __restrict__ Q,
                                                     const float* __restrict__ Km,
                                                     float* __restrict__ scores,
                                                     int h0)
{
  const int bn = blockIdx.x, bm = blockIdx.y, hh = blockIdx.z;
  const int h = h0 + hh;
  __shared__ float Qs[64][128];
  __shared__ float Ks[64][128];
  const int t  = threadIdx.x;
  const int tx = t & 15, ty = t >> 4;
  const int m0 = bm * 128, n0 = bn * 128;

  const int r   = t >> 1;          // 0..127
  const int kb0 = (t & 1) * 32;    // 0 or 32
#pragma unroll
  for (int f = 0; f < 8; ++f) {
    const int kc = kb0 + f*4;
    float4 q = *(const float4*)&Q [(size_t)(m0 + r) * 1024 + h*64 + kc];
    Qs[kc+0][r] = q.x; Qs[kc+1][r] = q.y; Qs[kc+2][r] = q.z; Qs[kc+3][r] = q.w;
    float4 k = *(const float4*)&Km[(size_t)(n0 + r) * 1024 + h*64 + kc];
    Ks[kc+0][r] = k.x; Ks[kc+1][r] = k.y; Ks[kc+2][r] = k.z; Ks[kc+3][r] = k.w;
  }
  __syncthreads();

  float acc[8][8];
#pragma unroll
  for (int i = 0; i < 8; ++i)
#pragma unroll
    for (int j = 0; j < 8; ++j) acc[i][j] = 0.f;

  for (int k = 0; k < 64; ++k) {
    float av[8], bv[8];
    *(float4*)&av[0] = *(const float4*)&Qs[k][ty*8];
    *(float4*)&av[4] = *(const float4*)&Qs[k][ty*8 + 4];
    *(float4*)&bv[0] = *(const float4*)&Ks[k][tx*8];
    *(float4*)&bv[4] = *(const float4*)&Ks[k][tx*8 + 4];
#pragma unroll
    for (int i = 0; i < 8; ++i)
#pragma unroll
      for (int j = 0; j < 8; ++j)
        acc[i][j] = fmaf(av[i], bv[j], acc[i][j]);
  }

#pragma unroll
  for (int i = 0; i < 8; ++i) {
    const int row = m0 + ty*8 + i;
#pragma unroll
    for (int j4 = 0; j4 < 2; ++j4) {
      const int col = n0 + tx*8 + j4*4;
      float4 o;
      o.x = acc[i][j4*4+0] * 0.125f;
      o.y = acc[i][j4*4+1] * 0.125f;
      o.z = acc[i][j4*4+2] * 0.125f;
      o.w = acc[i][j4*4+3] * 0.125f;
      *(float4*)&scores[((size_t)hh * SS + row) * SS + col] = o;
    }
  }
}

// ---------------- radix select (exact quantile) ----------------
__global__ __launch_bounds__(256) void init_state(unsigned* __restrict__ state,
                                                  unsigned* __restrict__ hist,
                                                  unsigned* __restrict__ ccnt, int cnt)
{
  const int t = threadIdx.x;
  for (int i = t; i < HH * 512; i += 256) hist[i] = 0;   // full clear, cnt-independent
  if (t < HH) ccnt[t] = 0;
  if (t < cnt) {
    state[t*4+0] = 0u; state[t*4+1] = K_A;
    state[t*4+2] = 0u; state[t*4+3] = K_B;
  }
}

__global__ __launch_bounds__(256) void hist_pass(const float* __restrict__ scores,
                                                 unsigned* __restrict__ hist,
                                                 const unsigned* __restrict__ state,
                                                 int shift, unsigned himask)
{
  const int hh = blockIdx.y;
  __shared__ unsigned lh0[256], lh1[256];
  const int t = threadIdx.x;
  lh0[t] = 0; lh1[t] = 0;
  __syncthreads();
  const unsigned prefA = state[hh*4+0];
  const unsigned prefB = state[hh*4+2];
  const float4* base = (const float4*)(scores + (size_t)hh * SS * SS)
                       + (size_t)blockIdx.x * 16384;
  for (int i = t; i < 16384; i += 256) {
    float4 v = base[i];
    unsigned u;
    u = sortkey(v.x);
    if ((u & himask) == prefA) atomicAdd(&lh0[(u >> shift) & 255], 1u);
    if ((u & himask) == prefB) atomicAdd(&lh1[(u >> shift) & 255], 1u);
    u = sortkey(v.y);
    if ((u & himask) == prefA) atomicAdd(&lh0[(u >> shift) & 255], 1u);
    if ((u & himask) == prefB) atomicAdd(&lh1[(u >> shift) & 255], 1u);
    u = sortkey(v.z);
    if ((u & himask) == prefA) atomicAdd(&lh0[(u >> shift) & 255], 1u);
    if ((u & himask) == prefB) atomicAdd(&lh1[(u >> shift) & 255], 1u);
    u = sortkey(v.w);
    if ((u & himask) == prefA) atomicAdd(&lh0[(u >> shift) & 255], 1u);
    if ((u & himask) == prefB) atomicAdd(&lh1[(u >> shift) & 255], 1u);
  }
  __syncthreads();
  if (lh0[t]) atomicAdd(&hist[(hh*2 + 0)*256 + t], lh0[t]);
  if (lh1[t]) atomicAdd(&hist[(hh*2 + 1)*256 + t], lh1[t]);
}

// pass 2: histogram bits 15..8 under 16-bit prefix AND compact matching sortkeys.
// Two-phase compaction: LDS buffer per block, ONE global atomic per block to
// reserve a range (round-4 post-mortem: per-match device-scope atomics to one
// cache line from 512 blocks serialized cross-XCD -> 586us with all pipes idle).
__global__ __launch_bounds__(256) void hist_compact(const float* __restrict__ scores,
                                                    unsigned* __restrict__ hist,
                                                    const unsigned* __restrict__ state,
                                                    unsigned* __restrict__ cand,
                                                    unsigned* __restrict__ ccnt)
{
  const int hh = blockIdx.y;
  __shared__ unsigned lh0[256], lh1[256];
  __shared__ unsigned lbuf[LCAP];
  __shared__ unsigned lcnt, gbase;
  const int t = threadIdx.x;
  lh0[t] = 0; lh1[t] = 0;
  if (t == 0) lcnt = 0;
  __syncthreads();
  const unsigned prefA = state[hh*4+0];
  const unsigned prefB = state[hh*4+2];
  unsigned* __restrict__ mycand = cand + (size_t)hh * CAPC;
  const float4* base = (const float4*)(scores + (size_t)hh * SS * SS)
                       + (size_t)blockIdx.x * 16384;
  for (int i = t; i < 16384; i += 256) {
    float4 v = base[i];
#pragma unroll
    for (int e = 0; e < 4; ++e) {
      const float f = (e == 0) ? v.x : (e == 1) ? v.y : (e == 2) ? v.z : v.w;
      const unsigned u = sortkey(f);
      const bool a = ((u & 0xFFFF0000u) == prefA);
      const bool b = ((u & 0xFFFF0000u) == prefB);
      if (a) atomicAdd(&lh0[(u >> 8) & 255], 1u);
      if (b) atomicAdd(&lh1[(u >> 8) & 255], 1u);
      if (a | b) {
        unsigned id = atomicAdd(&lcnt, 1u);
        if (id < LCAP) lbuf[id] = u;
        else { unsigned g = atomicAdd(&ccnt[hh], 1u); if (g < CAPC) mycand[g] = u; }
      }
    }
  }
  __syncthreads();
  const unsigned n = (lcnt < LCAP) ? lcnt : LCAP;
  if (t == 0) gbase = n ? atomicAdd(&ccnt[hh], n) : 0u;
  __syncthreads();
  const unsigned gb = gbase;
  for (unsigned i = t; i < n; i += 256)
    if (gb + i < CAPC) mycand[gb + i] = lbuf[i];
  if (lh0[t]) atomicAdd(&hist[(hh*2 + 0)*256 + t], lh0[t]);
  if (lh1[t]) atomicAdd(&hist[(hh*2 + 1)*256 + t], lh1[t]);
}

__global__ __launch_bounds__(256) void scan_pass(unsigned* __restrict__ hist,
                                                 unsigned* __restrict__ state,
                                                 float* __restrict__ thr,
                                                 int shift, int cnt)
{
  const int t = threadIdx.x;
  if (t < cnt) {
    float vals[2];
    for (int tgt = 0; tgt < 2; ++tgt) {
      unsigned pref = state[t*4 + tgt*2];
      unsigned k    = state[t*4 + tgt*2 + 1];
      unsigned cum = 0; int b = 0;
      for (; b < 256; ++b) {
        unsigned c = hist[(t*2 + tgt)*256 + b];
        if (cum + c > k) break;
        cum += c;
      }
      if (b == 256) b = 255;  // defensive
      pref |= ((unsigned)b) << shift;
      k -= cum;
      state[t*4 + tgt*2]     = pref;
      state[t*4 + tgt*2 + 1] = k;
      if (shift == 0) vals[tgt] = inv_sortkey(pref);
    }
    if (shift == 0) thr[t] = vals[0] + QFRAC * (vals[1] - vals[0]);
  }
  __syncthreads();
  for (int i = t; i < HH * 512; i += 256) hist[i] = 0;  // full clear for next pass
}

// last 8-bit digit from the candidate list (replaces a full 268 MB pass)
__global__ __launch_bounds__(256) void final_select(const unsigned* __restrict__ cand,
                                                    const unsigned* __restrict__ ccnt,
                                                    const unsigned* __restrict__ state,
                                                    float* __restrict__ thr)
{
  const int hh = blockIdx.x;
  const int t = threadIdx.x;
  __shared__ unsigned h0[256], h1[256];
  h0[t] = 0; h1[t] = 0;
  __syncthreads();
  const unsigned prefA = state[hh*4+0], kA = state[hh*4+1];
  const unsigned prefB = state[hh*4+2], kB = state[hh*4+3];
  unsigned n = ccnt[hh]; if (n > CAPC) n = CAPC;
  const unsigned* __restrict__ list = cand + (size_t)hh * CAPC;
  for (unsigned i = t; i < n; i += 256) {
    unsigned u = list[i];
    if ((u & 0xFFFFFF00u) == prefA) atomicAdd(&h0[u & 255], 1u);
    if ((u & 0xFFFFFF00u) == prefB) atomicAdd(&h1[u & 255], 1u);
  }
  __syncthreads();
  if (t == 0) {
    unsigned cum = 0; int b = 0;
    for (; b < 256; ++b) { unsigned c = h0[b]; if (cum + c > kA) break; cum += c; }
    if (b == 256) b = 255;
    const float vA = inv_sortkey(prefA | (unsigned)b);
    cum = 0; int b2 = 0;
    for (; b2 < 256; ++b2) { unsigned c = h1[b2]; if (cum + c > kB) break; cum += c; }
    if (b2 == 256) b2 = 255;
    const float vB = inv_sortkey(prefB | (unsigned)b2);
    thr[hh] = vA + QFRAC * (vB - vA);
  }
}

// ---------------- wave-per-row masked softmax + ballot-compacted sparse PV ----------------
__global__ __launch_bounds__(256) void softmax_pv2(const float* __restrict__ scores,
                                                   const float* __restrict__ thrArr,
                                                   const float* __restrict__ V,
                                                   float* __restrict__ ctx,
                                                   int h0)
{
  const int wave = threadIdx.x >> 6;
  const int lane = threadIdx.x & 63;
  const int row  = blockIdx.x * 4 + wave;
  const int hh   = blockIdx.y;
  const int h    = h0 + hh;
  const float thr = thrArr[hh];
  const float* __restrict__ srow = scores + ((size_t)hh * SS + row) * SS;

  float p[32];
#pragma unroll
  for (int t = 0; t < 32; ++t) p[t] = srow[t*64 + lane];

  float m = -INFINITY;
#pragma unroll
  for (int t = 0; t < 32; ++t)
    if (p[t] >= thr) m = fmaxf(m, p[t]);
#pragma unroll
  for (int off = 32; off; off >>= 1) m = fmaxf(m, __shfl_xor(m, off));

  float sum = 0.f;
#pragma unroll
  for (int t = 0; t < 32; ++t) {
    float e = (p[t] >= thr) ? __expf(p[t] - m) : 0.f;
    p[t] = e;
    sum += e;
  }
#pragma unroll
  for (int off = 32; off; off >>= 1) sum += __shfl_xor(sum, off);

  float acc0 = 0.f, acc1 = 0.f;
  const float* __restrict__ vcol = V + h*64 + lane;
#pragma unroll
  for (int t = 0; t < 32; ++t) {
    unsigned long long mk = __ballot(p[t] != 0.f);
    const float* __restrict__ vt = vcol + (size_t)t * 64 * 1024;
    while (mk) {
      int b0 = __ffsll(mk) - 1; mk &= mk - 1;
      if (mk) {
        int b1 = __ffsll(mk) - 1; mk &= mk - 1;
        float va = vt[(size_t)b0 * 1024];
        float vb = vt[(size_t)b1 * 1024];
        acc0 = fmaf(__shfl(p[t], b0), va, acc0);
        acc1 = fmaf(__shfl(p[t], b1), vb, acc1);
      } else {
        acc0 = fmaf(__shfl(p[t], b0), vt[(size_t)b0 * 1024], acc0);
      }
    }
  }
  ctx[(size_t)row * 1024 + h*64 + lane] = (acc0 + acc1) / sum;
}

// ---------------- host ----------------
extern "C" void kernel_launch(void* const* d_in, const int* in_sizes, int n_in,
                              void* d_out, int out_size, void* d_ws, size_t ws_size,
                              hipStream_t stream)
{
  const float* x  = (const float*)d_in[0];
  const float* Wq = (const float*)d_in[1];
  const float* bq = (const float*)d_in[2];
  const float* Wk = (const float*)d_in[3];
  const float* bk = (const float*)d_in[4];
  const float* Wv = (const float*)d_in[5];
  const float* bv = (const float*)d_in[6];
  const float* Wo = (const float*)d_in[7];
  const float* bo = (const float*)d_in[8];
  float* out = (float*)d_out;
  char*  ws  = (char*)d_ws;

  const size_t SD = (size_t)SS * DD * sizeof(float);  // 8 MiB
  float*    Q     = (float*)(ws + 0*SD);
  float*    K     = (float*)(ws + 1*SD);
  float*    V     = (float*)(ws + 2*SD);
  float*    ctx   = (float*)(ws + 3*SD);
  unsigned* state = (unsigned*)(ws + 4*SD);
  float*    thr   = (float*)(ws + 4*SD + 4096);
  unsigned* ccnt  = (unsigned*)(ws + 4*SD + 8192);
  unsigned* hist  = (unsigned*)(ws + 4*SD + 16384);    // 32 KiB
  unsigned* cand  = (unsigned*)(ws + 4*SD + 65536);    // HH * CAPC * 4 = 4 MiB
  const size_t off_scores = 4*SD + 65536 + (size_t)HH * CAPC * 4;
  float* scores = (float*)(ws + off_scores);
  const size_t perHead = (size_t)SS * SS * sizeof(float);  // 16 MiB

  int CH = 1;
  if (ws_size > off_scores + perHead)
    CH = (int)((ws_size - off_scores) / perHead);
  if (CH > HH) CH = HH;
  if (CH < 1)  CH = 1;

  gemm_qkv<<<dim3(16, 32, 3), 256, 0, stream>>>(x, Wq, bq, Wk, bk, Wv, bv, Q, K, V);

  for (int h0 = 0; h0 < HH; h0 += CH) {
    const int cnt = (HH - h0 < CH) ? (HH - h0) : CH;
    scores_kernel<<<dim3(16, 16, cnt), 256, 0, stream>>>(Q, K, scores, h0);
    init_state<<<1, 256, 0, stream>>>(state, hist, ccnt, cnt);
    // pass 0: bits 31..24 (full read)
    hist_pass<<<dim3(64, cnt), 256, 0, stream>>>(scores, hist, state, 24, 0u);
    scan_pass<<<1, 256, 0, stream>>>(hist, state, thr, 24, cnt);
    // pass 1: bits 23..16 (full read)
    hist_pass<<<dim3(64, cnt), 256, 0, stream>>>(scores, hist, state, 16, 0xFF000000u);
    scan_pass<<<1, 256, 0, stream>>>(hist, state, thr, 16, cnt);
    // pass 2: bits 15..8 (full read) + two-phase candidate compaction
    hist_compact<<<dim3(64, cnt), 256, 0, stream>>>(scores, hist, state, cand, ccnt);
    scan_pass<<<1, 256, 0, stream>>>(hist, state, thr, 8, cnt);
    // pass 3: bits 7..0 from candidate list only
    final_select<<<cnt, 256, 0, stream>>>(cand, ccnt, state, thr);
    softmax_pv2<<<dim3(SS/4, cnt), 256, 0, stream>>>(scores, thr, V, ctx, h0);
  }

  gemm_single<<<dim3(16, 32), 256, 0, stream>>>(ctx, Wo, bo, out);
}

// Round 6
// 836.540 us; speedup vs baseline: 2.0672x; 1.2844x over previous
//
#include <hip/hip_runtime.h>
#include <math.h>

#define SS 2048
#define DD 1024
#define HH 16
#define CAPC 49152u   // candidate slots per head (expected ~22K at 14-bit bins)
#define LCAP 2048     // per-block LDS candidate buffer (expected ~350/block)

// quantile index: floor(0.95*(S*S-1)) = floor(3984587.85)
#define K_A 3984587u
#define K_B 3984588u
#define QFRAC 0.85f

__device__ __forceinline__ unsigned sortkey(float f) {
  unsigned b = __float_as_uint(f);
  return (b & 0x80000000u) ? ~b : (b | 0x80000000u);
}
__device__ __forceinline__ float inv_sortkey(unsigned u) {
  unsigned b = (u & 0x80000000u) ? (u ^ 0x80000000u) : ~u;
  return __uint_as_float(b);
}

// ---------------- fp32 GEMM 64x64 (kept for gemm_single) ----------------
__device__ __forceinline__ void gemm64(const float* __restrict__ A,
                                       const float* __restrict__ B,
                                       const float* __restrict__ bias,
                                       float* __restrict__ C,
                                       int bm, int bn)
{
  __shared__ float As[16][68];
  __shared__ float Bs[16][68];
  const int t  = threadIdx.x;
  const int tx = t & 15, ty = t >> 4;
  const int m0 = bm * 64, n0 = bn * 64;

  float acc[4][4];
#pragma unroll
  for (int i = 0; i < 4; ++i)
#pragma unroll
    for (int j = 0; j < 4; ++j) acc[i][j] = 0.f;

  const int ar = t >> 2;
  const int ak = (t & 3) * 4;
  const int br = t >> 4;
  const int bc = (t & 15) * 4;

  for (int kb = 0; kb < 1024; kb += 16) {
    float4 a0 = *(const float4*)&A[(size_t)(m0 + ar) * 1024 + kb + ak];
    float4 b0 = *(const float4*)&B[(size_t)(kb + br) * 1024 + n0 + bc];
    __syncthreads();
    As[ak+0][ar] = a0.x; As[ak+1][ar] = a0.y; As[ak+2][ar] = a0.z; As[ak+3][ar] = a0.w;
    *(float4*)&Bs[br][bc] = b0;
    __syncthreads();
#pragma unroll
    for (int k = 0; k < 16; ++k) {
      float4 av = *(const float4*)&As[k][ty*4];
      float4 bv = *(const float4*)&Bs[k][tx*4];
      acc[0][0] = fmaf(av.x, bv.x, acc[0][0]); acc[0][1] = fmaf(av.x, bv.y, acc[0][1]);
      acc[0][2] = fmaf(av.x, bv.z, acc[0][2]); acc[0][3] = fmaf(av.x, bv.w, acc[0][3]);
      acc[1][0] = fmaf(av.y, bv.x, acc[1][0]); acc[1][1] = fmaf(av.y, bv.y, acc[1][1]);
      acc[1][2] = fmaf(av.y, bv.z, acc[1][2]); acc[1][3] = fmaf(av.y, bv.w, acc[1][3]);
      acc[2][0] = fmaf(av.z, bv.x, acc[2][0]); acc[2][1] = fmaf(av.z, bv.y, acc[2][1]);
      acc[2][2] = fmaf(av.z, bv.z, acc[2][2]); acc[2][3] = fmaf(av.z, bv.w, acc[2][3]);
      acc[3][0] = fmaf(av.w, bv.x, acc[3][0]); acc[3][1] = fmaf(av.w, bv.y, acc[3][1]);
      acc[3][2] = fmaf(av.w, bv.z, acc[3][2]); acc[3][3] = fmaf(av.w, bv.w, acc[3][3]);
    }
  }
#pragma unroll
  for (int i = 0; i < 4; ++i) {
    const int row = m0 + ty*4 + i;
    const int col = n0 + tx*4;
    float4 o;
    o.x = acc[i][0] + bias[col+0];
    o.y = acc[i][1] + bias[col+1];
    o.z = acc[i][2] + bias[col+2];
    o.w = acc[i][3] + bias[col+3];
    *(float4*)&C[(size_t)row * 1024 + col] = o;
  }
}

// ---------------- fp32 GEMM 64x128 tile (qkv): 32 FMA per 3 LDS-b128 reads ----------------
// Same ascending-k FMA chain per output element as gemm64 -> bitwise-identical results.
__device__ __forceinline__ void gemm64x128(const float* __restrict__ A,
                                           const float* __restrict__ B,
                                           const float* __restrict__ bias,
                                           float* __restrict__ C,
                                           int bm, int bn)
{
  __shared__ float As[16][68];
  __shared__ float Bs[16][132];
  const int t  = threadIdx.x;
  const int tx = t & 15, ty = t >> 4;
  const int m0 = bm * 64, n0 = bn * 128;

  float acc[4][8];
#pragma unroll
  for (int i = 0; i < 4; ++i)
#pragma unroll
    for (int j = 0; j < 8; ++j) acc[i][j] = 0.f;

  const int ar = t >> 2;          // A row 0..63 (1 float4/thread)
  const int ak = (t & 3) * 4;
  const int br = t >> 4;          // B row 0..15 (2 float4/thread)
  const int bc = (t & 15) * 8;

  for (int kb = 0; kb < 1024; kb += 16) {
    float4 a0 = *(const float4*)&A[(size_t)(m0 + ar) * 1024 + kb + ak];
    float4 b0 = *(const float4*)&B[(size_t)(kb + br) * 1024 + n0 + bc];
    float4 b1 = *(const float4*)&B[(size_t)(kb + br) * 1024 + n0 + bc + 4];
    __syncthreads();
    As[ak+0][ar] = a0.x; As[ak+1][ar] = a0.y; As[ak+2][ar] = a0.z; As[ak+3][ar] = a0.w;
    *(float4*)&Bs[br][bc]     = b0;
    *(float4*)&Bs[br][bc + 4] = b1;
    __syncthreads();
#pragma unroll
    for (int k = 0; k < 16; ++k) {
      float4 av  = *(const float4*)&As[k][ty*4];
      float4 bv0 = *(const float4*)&Bs[k][tx*8];
      float4 bv1 = *(const float4*)&Bs[k][tx*8 + 4];
      float a4[4]; a4[0]=av.x; a4[1]=av.y; a4[2]=av.z; a4[3]=av.w;
#pragma unroll
      for (int i = 0; i < 4; ++i) {
        acc[i][0] = fmaf(a4[i], bv0.x, acc[i][0]);
        acc[i][1] = fmaf(a4[i], bv0.y, acc[i][1]);
        acc[i][2] = fmaf(a4[i], bv0.z, acc[i][2]);
        acc[i][3] = fmaf(a4[i], bv0.w, acc[i][3]);
        acc[i][4] = fmaf(a4[i], bv1.x, acc[i][4]);
        acc[i][5] = fmaf(a4[i], bv1.y, acc[i][5]);
        acc[i][6] = fmaf(a4[i], bv1.z, acc[i][6]);
        acc[i][7] = fmaf(a4[i], bv1.w, acc[i][7]);
      }
    }
  }
#pragma unroll
  for (int i = 0; i < 4; ++i) {
    const int row = m0 + ty*4 + i;
    const int col = n0 + tx*8;
    float4 o0, o1;
    o0.x = acc[i][0] + bias[col+0];
    o0.y = acc[i][1] + bias[col+1];
    o0.z = acc[i][2] + bias[col+2];
    o0.w = acc[i][3] + bias[col+3];
    o1.x = acc[i][4] + bias[col+4];
    o1.y = acc[i][5] + bias[col+5];
    o1.z = acc[i][6] + bias[col+6];
    o1.w = acc[i][7] + bias[col+7];
    *(float4*)&C[(size_t)row * 1024 + col]     = o0;
    *(float4*)&C[(size_t)row * 1024 + col + 4] = o1;
  }
}

__global__ __launch_bounds__(256) void gemm_qkv(const float* __restrict__ x,
    const float* __restrict__ Wq, const float* __restrict__ bq,
    const float* __restrict__ Wk, const float* __restrict__ bk,
    const float* __restrict__ Wv, const float* __restrict__ bv,
    float* __restrict__ Q, float* __restrict__ K, float* __restrict__ V)
{
  const int z = blockIdx.z;
  const float* W = (z == 0) ? Wq : (z == 1) ? Wk : Wv;
  const float* b = (z == 0) ? bq : (z == 1) ? bk : bv;
  float*       O = (z == 0) ? Q  : (z == 1) ? K  : V;
  gemm64x128(x, W, b, O, blockIdx.y, blockIdx.x);
}

__global__ __launch_bounds__(256) void gemm_single(const float* __restrict__ A,
    const float* __restrict__ W, const float* __restrict__ b, float* __restrict__ O)
{
  gemm64(A, W, b, O, blockIdx.y, blockIdx.x);
}

// ---------------- scores[hh][i][j] = (Q_h[i,:] . K_h[j,:]) / 8 ----------------
__global__ __launch_bounds__(256) void scores_kernel(const float* __restrict__ Q,
                                                     const float* __restrict__ Km,
                                                     float* __restrict__ scores,
                                                     int h0)
{
  const int bn = blockIdx.x, bm = blockIdx.y, hh = blockIdx.z;
  const int h = h0 + hh;
  __shared__ float Qs[64][128];
  __shared__ float Ks[64][128];
  const int t  = threadIdx.x;
  const int tx = t & 15, ty = t >> 4;
  const int m0 = bm * 128, n0 = bn * 128;

  const int r   = t >> 1;
  const int kb0 = (t & 1) * 32;
#pragma unroll
  for (int f = 0; f < 8; ++f) {
    const int kc = kb0 + f*4;
    float4 q = *(const float4*)&Q [(size_t)(m0 + r) * 1024 + h*64 + kc];
    Qs[kc+0][r] = q.x; Qs[kc+1][r] = q.y; Qs[kc+2][r] = q.z; Qs[kc+3][r] = q.w;
    float4 k = *(const float4*)&Km[(size_t)(n0 + r) * 1024 + h*64 + kc];
    Ks[kc+0][r] = k.x; Ks[kc+1][r] = k.y; Ks[kc+2][r] = k.z; Ks[kc+3][r] = k.w;
  }
  __syncthreads();

  float acc[8][8];
#pragma unroll
  for (int i = 0; i < 8; ++i)
#pragma unroll
    for (int j = 0; j < 8; ++j) acc[i][j] = 0.f;

  for (int k = 0; k < 64; ++k) {
    float av[8], bv[8];
    *(float4*)&av[0] = *(const float4*)&Qs[k][ty*8];
    *(float4*)&av[4] = *(const float4*)&Qs[k][ty*8 + 4];
    *(float4*)&bv[0] = *(const float4*)&Ks[k][tx*8];
    *(float4*)&bv[4] = *(const float4*)&Ks[k][tx*8 + 4];
#pragma unroll
    for (int i = 0; i < 8; ++i)
#pragma unroll
      for (int j = 0; j < 8; ++j)
        acc[i][j] = fmaf(av[i], bv[j], acc[i][j]);
  }

#pragma unroll
  for (int i = 0; i < 8; ++i) {
    const int row = m0 + ty*8 + i;
#pragma unroll
    for (int j4 = 0; j4 < 2; ++j4) {
      const int col = n0 + tx*8 + j4*4;
      float4 o;
      o.x = acc[i][j4*4+0] * 0.125f;
      o.y = acc[i][j4*4+1] * 0.125f;
      o.z = acc[i][j4*4+2] * 0.125f;
      o.w = acc[i][j4*4+3] * 0.125f;
      *(float4*)&scores[((size_t)hh * SS + row) * SS + col] = o;
    }
  }
}

// ---------------- radix select, 14-bit first digit ----------------
__global__ __launch_bounds__(256) void init14(unsigned* __restrict__ ghist,
                                              unsigned* __restrict__ ccnt)
{
  int i = blockIdx.x * 256 + threadIdx.x;
  for (; i < HH * 16384; i += gridDim.x * 256) ghist[i] = 0;
  if (blockIdx.x == 0 && threadIdx.x < HH) ccnt[threadIdx.x] = 0;
}

// full read: 16384-bin LDS histogram of sortkey>>18, flushed to global per head
__global__ __launch_bounds__(512) void hist14(const float* __restrict__ scores,
                                              unsigned* __restrict__ ghist)
{
  const int hh = blockIdx.y;
  __shared__ unsigned lh[16384];   // 64 KB
  const int t = threadIdx.x;
  for (int i = t; i < 16384; i += 512) lh[i] = 0;
  __syncthreads();
  const float4* base = (const float4*)(scores + (size_t)hh * SS * SS)
                       + (size_t)blockIdx.x * 16384;
  for (int i = t; i < 16384; i += 512) {
    float4 v = base[i];
    atomicAdd(&lh[sortkey(v.x) >> 18], 1u);
    atomicAdd(&lh[sortkey(v.y) >> 18], 1u);
    atomicAdd(&lh[sortkey(v.z) >> 18], 1u);
    atomicAdd(&lh[sortkey(v.w) >> 18], 1u);
  }
  __syncthreads();
  unsigned* __restrict__ gh = ghist + (size_t)hh * 16384;
  for (int i = t; i < 16384; i += 512) {
    const unsigned c = lh[i];
    if (c) atomicAdd(&gh[i], c);
  }
}

// find the 14-bit bins holding ranks K_A and K_B=K_A+1 (O(1) second-bin rule)
__global__ __launch_bounds__(256) void scan14(const unsigned* __restrict__ ghist,
                                              unsigned* __restrict__ state)
{
  const int hh = blockIdx.x;
  const int t = threadIdx.x;
  __shared__ unsigned part[256];
  __shared__ unsigned out[4];
  const unsigned* __restrict__ hb = ghist + (size_t)hh * 16384;
  unsigned s = 0;
  for (int j = 0; j < 64; ++j) s += hb[t*64 + j];
  part[t] = s;
  __syncthreads();
  if (t == 0) {
    unsigned run = 0;
    for (int i = 0; i < 256; ++i) { unsigned tmp = part[i]; part[i] = run; run += tmp; }
  }
  __syncthreads();
  const unsigned cum0 = part[t];
  if (K_A >= cum0 && K_A < cum0 + s) {
    unsigned c2 = cum0;
    for (int j = 0; j < 64; ++j) {
      const unsigned c = hb[t*64 + j];
      if (K_A < c2 + c) {
        const unsigned binA = t*64 + j;
        const unsigned residA = K_A - c2;
        unsigned binB, residB;
        if (residA + 1 < c) { binB = binA; residB = residA + 1; }
        else {
          unsigned bb = binA + 1;
          while (bb < 16384 && hb[bb] == 0) ++bb;
          if (bb >= 16384) bb = 16383;  // defensive
          binB = bb; residB = 0;
        }
        out[0] = binA; out[1] = residA; out[2] = binB; out[3] = residB;
        break;
      }
      c2 += c;
    }
  }
  __syncthreads();
  if (t < 4) state[hh*4 + t] = out[t];
}

// full read: compact sortkeys in bins A/B (two-phase LDS reservation, round-5 pattern)
__global__ __launch_bounds__(512) void compact14(const float* __restrict__ scores,
                                                 const unsigned* __restrict__ state,
                                                 unsigned* __restrict__ cand,
                                                 unsigned* __restrict__ ccnt)
{
  const int hh = blockIdx.y;
  __shared__ unsigned lbuf[LCAP];
  __shared__ unsigned lcnt, gbase;
  const int t = threadIdx.x;
  if (t == 0) lcnt = 0;
  __syncthreads();
  const unsigned binA = state[hh*4+0];
  const unsigned binB = state[hh*4+2];
  unsigned* __restrict__ mycand = cand + (size_t)hh * CAPC;
  const float4* base = (const float4*)(scores + (size_t)hh * SS * SS)
                       + (size_t)blockIdx.x * 16384;
  for (int i = t; i < 16384; i += 512) {
    float4 v = base[i];
#pragma unroll
    for (int e = 0; e < 4; ++e) {
      const float f = (e == 0) ? v.x : (e == 1) ? v.y : (e == 2) ? v.z : v.w;
      const unsigned u = sortkey(f);
      const unsigned bin = u >> 18;
      if (bin == binA || bin == binB) {
        unsigned id = atomicAdd(&lcnt, 1u);
        if (id < LCAP) lbuf[id] = u;
        else { unsigned g = atomicAdd(&ccnt[hh], 1u); if (g < CAPC) mycand[g] = u; }
      }
    }
  }
  __syncthreads();
  const unsigned n = (lcnt < LCAP) ? lcnt : LCAP;
  if (t == 0) gbase = n ? atomicAdd(&ccnt[hh], n) : 0u;
  __syncthreads();
  const unsigned gb = gbase;
  for (unsigned i = t; i < n; i += 512)
    if (gb + i < CAPC) mycand[gb + i] = lbuf[i];
}

// resolve remaining 18 bits (8+8+2) from the candidate list; histogram order-invariant
__global__ __launch_bounds__(256) void final_select_list(const unsigned* __restrict__ cand,
                                                         const unsigned* __restrict__ ccnt,
                                                         const unsigned* __restrict__ state,
                                                         float* __restrict__ thr)
{
  const int hh = blockIdx.x;
  const int t = threadIdx.x;
  __shared__ unsigned hist[256];
  __shared__ unsigned digitS, kresS;
  __shared__ float valS[2];
  unsigned n = ccnt[hh]; if (n > CAPC) n = CAPC;
  const unsigned* __restrict__ list = cand + (size_t)hh * CAPC;
  for (int tgt = 0; tgt < 2; ++tgt) {
    unsigned pfx = state[hh*4 + tgt*2];      // 14-bit bin id
    unsigned k   = state[hh*4 + tgt*2 + 1];  // residual rank within bin
    for (int r = 0; r < 3; ++r) {
      const int s = (r == 0) ? 10 : (r == 1) ? 2 : 0;
      const int w = (r == 2) ? 2 : 8;
      const unsigned nb = 1u << w;
      hist[t] = 0;
      __syncthreads();
      for (unsigned i = t; i < n; i += 256) {
        const unsigned u = list[i];
        if ((u >> (s + w)) == pfx) atomicAdd(&hist[(u >> s) & (nb - 1)], 1u);
      }
      __syncthreads();
      if (t == 0) {
        unsigned cum = 0, b = 0;
        for (; b < nb; ++b) { const unsigned c = hist[b]; if (cum + c > k) break; cum += c; }
        if (b == nb) b = nb - 1;
        digitS = b; kresS = k - cum;
      }
      __syncthreads();
      pfx = (pfx << w) | digitS;
      k = kresS;
    }
    if (t == 0) valS[tgt] = inv_sortkey(pfx);
    __syncthreads();
  }
  if (t == 0) thr[hh] = valS[0] + QFRAC * (valS[1] - valS[0]);
}

// ---------------- wave-per-row masked softmax + ballot-compacted sparse PV ----------------
__global__ __launch_bounds__(256) void softmax_pv2(const float* __restrict__ scores,
                                                   const float* __restrict__ thrArr,
                                                   const float* __restrict__ V,
                                                   float* __restrict__ ctx,
                                                   int h0)
{
  const int wave = threadIdx.x >> 6;
  const int lane = threadIdx.x & 63;
  const int row  = blockIdx.x * 4 + wave;
  const int hh   = blockIdx.y;
  const int h    = h0 + hh;
  const float thr = thrArr[hh];
  const float* __restrict__ srow = scores + ((size_t)hh * SS + row) * SS;

  float p[32];
#pragma unroll
  for (int t = 0; t < 32; ++t) p[t] = srow[t*64 + lane];

  float m = -INFINITY;
#pragma unroll
  for (int t = 0; t < 32; ++t)
    if (p[t] >= thr) m = fmaxf(m, p[t]);
#pragma unroll
  for (int off = 32; off; off >>= 1) m = fmaxf(m, __shfl_xor(m, off));

  float sum = 0.f;
#pragma unroll
  for (int t = 0; t < 32; ++t) {
    float e = (p[t] >= thr) ? __expf(p[t] - m) : 0.f;
    p[t] = e;
    sum += e;
  }
#pragma unroll
  for (int off = 32; off; off >>= 1) sum += __shfl_xor(sum, off);

  float acc0 = 0.f, acc1 = 0.f;
  const float* __restrict__ vcol = V + h*64 + lane;
#pragma unroll
  for (int t = 0; t < 32; ++t) {
    unsigned long long mk = __ballot(p[t] != 0.f);
    const float* __restrict__ vt = vcol + (size_t)t * 64 * 1024;
    while (mk) {
      int b0 = __ffsll(mk) - 1; mk &= mk - 1;
      if (mk) {
        int b1 = __ffsll(mk) - 1; mk &= mk - 1;
        float va = vt[(size_t)b0 * 1024];
        float vb = vt[(size_t)b1 * 1024];
        acc0 = fmaf(__shfl(p[t], b0), va, acc0);
        acc1 = fmaf(__shfl(p[t], b1), vb, acc1);
      } else {
        acc0 = fmaf(__shfl(p[t], b0), vt[(size_t)b0 * 1024], acc0);
      }
    }
  }
  ctx[(size_t)row * 1024 + h*64 + lane] = (acc0 + acc1) / sum;
}

// ---------------- host ----------------
extern "C" void kernel_launch(void* const* d_in, const int* in_sizes, int n_in,
                              void* d_out, int out_size, void* d_ws, size_t ws_size,
                              hipStream_t stream)
{
  const float* x  = (const float*)d_in[0];
  const float* Wq = (const float*)d_in[1];
  const float* bq = (const float*)d_in[2];
  const float* Wk = (const float*)d_in[3];
  const float* bk = (const float*)d_in[4];
  const float* Wv = (const float*)d_in[5];
  const float* bv = (const float*)d_in[6];
  const float* Wo = (const float*)d_in[7];
  const float* bo = (const float*)d_in[8];
  float* out = (float*)d_out;
  char*  ws  = (char*)d_ws;

  const size_t SD = (size_t)SS * DD * sizeof(float);  // 8 MiB
  float*    Q     = (float*)(ws + 0*SD);
  float*    K     = (float*)(ws + 1*SD);
  float*    V     = (float*)(ws + 2*SD);
  float*    ctx   = (float*)(ws + 3*SD);
  unsigned* state = (unsigned*)(ws + 4*SD);
  float*    thr   = (float*)(ws + 4*SD + 4096);
  unsigned* ccnt  = (unsigned*)(ws + 4*SD + 8192);
  unsigned* ghist = (unsigned*)(ws + 4*SD + 16384);           // HH*16384*4 = 1 MiB
  unsigned* cand  = (unsigned*)(ws + 4*SD + 16384 + 1048576); // HH*CAPC*4 = 3 MiB
  const size_t off_scores = 4*SD + 16384 + 1048576 + (size_t)HH * CAPC * 4;
  float* scores = (float*)(ws + off_scores);
  const size_t perHead = (size_t)SS * SS * sizeof(float);  // 16 MiB

  int CH = 1;
  if (ws_size > off_scores + perHead)
    CH = (int)((ws_size - off_scores) / perHead);
  if (CH > HH) CH = HH;
  if (CH < 1)  CH = 1;

  gemm_qkv<<<dim3(8, 32, 3), 256, 0, stream>>>(x, Wq, bq, Wk, bk, Wv, bv, Q, K, V);

  for (int h0 = 0; h0 < HH; h0 += CH) {
    const int cnt = (HH - h0 < CH) ? (HH - h0) : CH;
    scores_kernel<<<dim3(16, 16, cnt), 256, 0, stream>>>(Q, K, scores, h0);
    init14<<<256, 256, 0, stream>>>(ghist, ccnt);
    hist14<<<dim3(64, cnt), 512, 0, stream>>>(scores, ghist);
    scan14<<<cnt, 256, 0, stream>>>(ghist, state);
    compact14<<<dim3(64, cnt), 512, 0, stream>>>(scores, state, cand, ccnt);
    final_select_list<<<cnt, 256, 0, stream>>>(cand, ccnt, state, thr);
    softmax_pv2<<<dim3(SS/4, cnt), 256, 0, stream>>>(scores, thr, V, ctx, h0);
  }

  gemm_single<<<dim3(16, 32), 256, 0, stream>>>(ctx, Wo, bo, out);
}

// Round 7
// 820.110 us; speedup vs baseline: 2.1086x; 1.0200x over previous
//
#include <hip/hip_runtime.h>
#include <math.h>

#define SS 2048
#define DD 1024
#define HH 16
#define CAPC 49152u   // candidate slots per head (expected ~22K at 14-bit bins)
#define LCAP 2048     // per-block LDS candidate buffer (expected ~350/block)

// quantile index: floor(0.95*(S*S-1)) = floor(3984587.85)
#define K_A 3984587u
#define K_B 3984588u
#define QFRAC 0.85f

__device__ __forceinline__ unsigned sortkey(float f) {
  unsigned b = __float_as_uint(f);
  return (b & 0x80000000u) ? ~b : (b | 0x80000000u);
}
__device__ __forceinline__ float inv_sortkey(unsigned u) {
  unsigned b = (u & 0x80000000u) ? (u ^ 0x80000000u) : ~u;
  return __uint_as_float(b);
}

// ---------------- fp32 GEMM 64x64 (kept for gemm_single) ----------------
__device__ __forceinline__ void gemm64(const float* __restrict__ A,
                                       const float* __restrict__ B,
                                       const float* __restrict__ bias,
                                       float* __restrict__ C,
                                       int bm, int bn)
{
  __shared__ float As[16][68];
  __shared__ float Bs[16][68];
  const int t  = threadIdx.x;
  const int tx = t & 15, ty = t >> 4;
  const int m0 = bm * 64, n0 = bn * 64;

  float acc[4][4];
#pragma unroll
  for (int i = 0; i < 4; ++i)
#pragma unroll
    for (int j = 0; j < 4; ++j) acc[i][j] = 0.f;

  const int ar = t >> 2;
  const int ak = (t & 3) * 4;
  const int br = t >> 4;
  const int bc = (t & 15) * 4;

  for (int kb = 0; kb < 1024; kb += 16) {
    float4 a0 = *(const float4*)&A[(size_t)(m0 + ar) * 1024 + kb + ak];
    float4 b0 = *(const float4*)&B[(size_t)(kb + br) * 1024 + n0 + bc];
    __syncthreads();
    As[ak+0][ar] = a0.x; As[ak+1][ar] = a0.y; As[ak+2][ar] = a0.z; As[ak+3][ar] = a0.w;
    *(float4*)&Bs[br][bc] = b0;
    __syncthreads();
#pragma unroll
    for (int k = 0; k < 16; ++k) {
      float4 av = *(const float4*)&As[k][ty*4];
      float4 bv = *(const float4*)&Bs[k][tx*4];
      acc[0][0] = fmaf(av.x, bv.x, acc[0][0]); acc[0][1] = fmaf(av.x, bv.y, acc[0][1]);
      acc[0][2] = fmaf(av.x, bv.z, acc[0][2]); acc[0][3] = fmaf(av.x, bv.w, acc[0][3]);
      acc[1][0] = fmaf(av.y, bv.x, acc[1][0]); acc[1][1] = fmaf(av.y, bv.y, acc[1][1]);
      acc[1][2] = fmaf(av.y, bv.z, acc[1][2]); acc[1][3] = fmaf(av.y, bv.w, acc[1][3]);
      acc[2][0] = fmaf(av.z, bv.x, acc[2][0]); acc[2][1] = fmaf(av.z, bv.y, acc[2][1]);
      acc[2][2] = fmaf(av.z, bv.z, acc[2][2]); acc[2][3] = fmaf(av.z, bv.w, acc[2][3]);
      acc[3][0] = fmaf(av.w, bv.x, acc[3][0]); acc[3][1] = fmaf(av.w, bv.y, acc[3][1]);
      acc[3][2] = fmaf(av.w, bv.z, acc[3][2]); acc[3][3] = fmaf(av.w, bv.w, acc[3][3]);
    }
  }
#pragma unroll
  for (int i = 0; i < 4; ++i) {
    const int row = m0 + ty*4 + i;
    const int col = n0 + tx*4;
    float4 o;
    o.x = acc[i][0] + bias[col+0];
    o.y = acc[i][1] + bias[col+1];
    o.z = acc[i][2] + bias[col+2];
    o.w = acc[i][3] + bias[col+3];
    *(float4*)&C[(size_t)row * 1024 + col] = o;
  }
}

// ---------------- fp32 GEMM 64x128 tile (qkv) ----------------
// Split-column fragments: thread owns cols {tx*4..+3} and {64+tx*4..+3}.
// ds_read lane stride = 4 floats -> 2-way bank aliasing (free); round-6's tx*8
// stride-8 layout was a 4-way conflict on every b128 read (2.99e7 conflicts).
// Per-element FMA chain unchanged (ascending k) -> bitwise-identical output.
__device__ __forceinline__ void gemm64x128(const float* __restrict__ A,
                                           const float* __restrict__ B,
                                           const float* __restrict__ bias,
                                           float* __restrict__ C,
                                           int bm, int bn)
{
  __shared__ float As[16][68];
  __shared__ float Bs[16][132];
  const int t  = threadIdx.x;
  const int tx = t & 15, ty = t >> 4;
  const int m0 = bm * 64, n0 = bn * 128;

  float acc[4][8];
#pragma unroll
  for (int i = 0; i < 4; ++i)
#pragma unroll
    for (int j = 0; j < 8; ++j) acc[i][j] = 0.f;

  const int ar = t >> 2;          // A row 0..63 (1 float4/thread)
  const int ak = (t & 3) * 4;
  const int br = t >> 4;          // B row 0..15 (2 float4/thread)
  const int bc = (t & 15) * 4;    // split: bc and 64+bc

  for (int kb = 0; kb < 1024; kb += 16) {
    float4 a0 = *(const float4*)&A[(size_t)(m0 + ar) * 1024 + kb + ak];
    float4 b0 = *(const float4*)&B[(size_t)(kb + br) * 1024 + n0 + bc];
    float4 b1 = *(const float4*)&B[(size_t)(kb + br) * 1024 + n0 + 64 + bc];
    __syncthreads();
    As[ak+0][ar] = a0.x; As[ak+1][ar] = a0.y; As[ak+2][ar] = a0.z; As[ak+3][ar] = a0.w;
    *(float4*)&Bs[br][bc]      = b0;
    *(float4*)&Bs[br][64 + bc] = b1;
    __syncthreads();
#pragma unroll
    for (int k = 0; k < 16; ++k) {
      float4 av  = *(const float4*)&As[k][ty*4];
      float4 bv0 = *(const float4*)&Bs[k][bc];        // wait: bc is per-thread tx*4
      float4 bv1 = *(const float4*)&Bs[k][64 + bc];
      float a4[4]; a4[0]=av.x; a4[1]=av.y; a4[2]=av.z; a4[3]=av.w;
#pragma unroll
      for (int i = 0; i < 4; ++i) {
        acc[i][0] = fmaf(a4[i], bv0.x, acc[i][0]);
        acc[i][1] = fmaf(a4[i], bv0.y, acc[i][1]);
        acc[i][2] = fmaf(a4[i], bv0.z, acc[i][2]);
        acc[i][3] = fmaf(a4[i], bv0.w, acc[i][3]);
        acc[i][4] = fmaf(a4[i], bv1.x, acc[i][4]);
        acc[i][5] = fmaf(a4[i], bv1.y, acc[i][5]);
        acc[i][6] = fmaf(a4[i], bv1.z, acc[i][6]);
        acc[i][7] = fmaf(a4[i], bv1.w, acc[i][7]);
      }
    }
  }
#pragma unroll
  for (int i = 0; i < 4; ++i) {
    const int row = m0 + ty*4 + i;
    const int c0 = n0 + tx*4;
    const int c1 = n0 + 64 + tx*4;
    float4 o0, o1;
    o0.x = acc[i][0] + bias[c0+0];
    o0.y = acc[i][1] + bias[c0+1];
    o0.z = acc[i][2] + bias[c0+2];
    o0.w = acc[i][3] + bias[c0+3];
    o1.x = acc[i][4] + bias[c1+0];
    o1.y = acc[i][5] + bias[c1+1];
    o1.z = acc[i][6] + bias[c1+2];
    o1.w = acc[i][7] + bias[c1+3];
    *(float4*)&C[(size_t)row * 1024 + c0] = o0;
    *(float4*)&C[(size_t)row * 1024 + c1] = o1;
  }
}

__global__ __launch_bounds__(256) void gemm_qkv(const float* __restrict__ x,
    const float* __restrict__ Wq, const float* __restrict__ bq,
    const float* __restrict__ Wk, const float* __restrict__ bk,
    const float* __restrict__ Wv, const float* __restrict__ bv,
    float* __restrict__ Q, float* __restrict__ K, float* __restrict__ V)
{
  const int z = blockIdx.z;
  const float* W = (z == 0) ? Wq : (z == 1) ? Wk : Wv;
  const float* b = (z == 0) ? bq : (z == 1) ? bk : bv;
  float*       O = (z == 0) ? Q  : (z == 1) ? K  : V;
  gemm64x128(x, W, b, O, blockIdx.y, blockIdx.x);
}

__global__ __launch_bounds__(256) void gemm_single(const float* __restrict__ A,
    const float* __restrict__ W, const float* __restrict__ b, float* __restrict__ O)
{
  gemm64(A, W, b, O, blockIdx.y, blockIdx.x);
}

// ---------------- scores[hh][i][j] = (Q_h[i,:] . K_h[j,:]) / 8 ----------------
// Same split-column fix on the Ks fragment (was tx*8 = 4-way conflict).
__global__ __launch_bounds__(256) void scores_kernel(const float* __restrict__ Q,
                                                     const float* __restrict__ Km,
                                                     float* __restrict__ scores,
                                                     int h0)
{
  const int bn = blockIdx.x, bm = blockIdx.y, hh = blockIdx.z;
  const int h = h0 + hh;
  __shared__ float Qs[64][128];
  __shared__ float Ks[64][128];
  const int t  = threadIdx.x;
  const int tx = t & 15, ty = t >> 4;
  const int m0 = bm * 128, n0 = bn * 128;

  const int r   = t >> 1;
  const int kb0 = (t & 1) * 32;
#pragma unroll
  for (int f = 0; f < 8; ++f) {
    const int kc = kb0 + f*4;
    float4 q = *(const float4*)&Q [(size_t)(m0 + r) * 1024 + h*64 + kc];
    Qs[kc+0][r] = q.x; Qs[kc+1][r] = q.y; Qs[kc+2][r] = q.z; Qs[kc+3][r] = q.w;
    float4 k = *(const float4*)&Km[(size_t)(n0 + r) * 1024 + h*64 + kc];
    Ks[kc+0][r] = k.x; Ks[kc+1][r] = k.y; Ks[kc+2][r] = k.z; Ks[kc+3][r] = k.w;
  }
  __syncthreads();

  float acc[8][8];
#pragma unroll
  for (int i = 0; i < 8; ++i)
#pragma unroll
    for (int j = 0; j < 8; ++j) acc[i][j] = 0.f;

  for (int k = 0; k < 64; ++k) {
    float av[8], bv[8];
    *(float4*)&av[0] = *(const float4*)&Qs[k][ty*8];
    *(float4*)&av[4] = *(const float4*)&Qs[k][ty*8 + 4];
    *(float4*)&bv[0] = *(const float4*)&Ks[k][tx*4];        // cols tx*4..+3
    *(float4*)&bv[4] = *(const float4*)&Ks[k][64 + tx*4];   // cols 64+tx*4..+3
#pragma unroll
    for (int i = 0; i < 8; ++i)
#pragma unroll
      for (int j = 0; j < 8; ++j)
        acc[i][j] = fmaf(av[i], bv[j], acc[i][j]);
  }

#pragma unroll
  for (int i = 0; i < 8; ++i) {
    const int row = m0 + ty*8 + i;
    const int c0 = n0 + tx*4;
    const int c1 = n0 + 64 + tx*4;
    float4 o0, o1;
    o0.x = acc[i][0] * 0.125f;
    o0.y = acc[i][1] * 0.125f;
    o0.z = acc[i][2] * 0.125f;
    o0.w = acc[i][3] * 0.125f;
    o1.x = acc[i][4] * 0.125f;
    o1.y = acc[i][5] * 0.125f;
    o1.z = acc[i][6] * 0.125f;
    o1.w = acc[i][7] * 0.125f;
    *(float4*)&scores[((size_t)hh * SS + row) * SS + c0] = o0;
    *(float4*)&scores[((size_t)hh * SS + row) * SS + c1] = o1;
  }
}

// ---------------- radix select, 14-bit first digit ----------------
__global__ __launch_bounds__(256) void init14(unsigned* __restrict__ ghist,
                                              unsigned* __restrict__ ccnt)
{
  int i = blockIdx.x * 256 + threadIdx.x;
  for (; i < HH * 16384; i += gridDim.x * 256) ghist[i] = 0;
  if (blockIdx.x == 0 && threadIdx.x < HH) ccnt[threadIdx.x] = 0;
}

// full read: 16384-bin LDS histogram of sortkey>>18, flushed to global per head
__global__ __launch_bounds__(512) void hist14(const float* __restrict__ scores,
                                              unsigned* __restrict__ ghist)
{
  const int hh = blockIdx.y;
  __shared__ unsigned lh[16384];   // 64 KB
  const int t = threadIdx.x;
  for (int i = t; i < 16384; i += 512) lh[i] = 0;
  __syncthreads();
  const float4* base = (const float4*)(scores + (size_t)hh * SS * SS)
                       + (size_t)blockIdx.x * 16384;
  for (int i = t; i < 16384; i += 512) {
    float4 v = base[i];
    atomicAdd(&lh[sortkey(v.x) >> 18], 1u);
    atomicAdd(&lh[sortkey(v.y) >> 18], 1u);
    atomicAdd(&lh[sortkey(v.z) >> 18], 1u);
    atomicAdd(&lh[sortkey(v.w) >> 18], 1u);
  }
  __syncthreads();
  unsigned* __restrict__ gh = ghist + (size_t)hh * 16384;
  for (int i = t; i < 16384; i += 512) {
    const unsigned c = lh[i];
    if (c) atomicAdd(&gh[i], c);
  }
}

// find the 14-bit bins holding ranks K_A and K_B=K_A+1 (O(1) second-bin rule)
__global__ __launch_bounds__(256) void scan14(const unsigned* __restrict__ ghist,
                                              unsigned* __restrict__ state)
{
  const int hh = blockIdx.x;
  const int t = threadIdx.x;
  __shared__ unsigned part[256];
  __shared__ unsigned out[4];
  const unsigned* __restrict__ hb = ghist + (size_t)hh * 16384;
  unsigned s = 0;
  for (int j = 0; j < 64; ++j) s += hb[t*64 + j];
  part[t] = s;
  __syncthreads();
  if (t == 0) {
    unsigned run = 0;
    for (int i = 0; i < 256; ++i) { unsigned tmp = part[i]; part[i] = run; run += tmp; }
  }
  __syncthreads();
  const unsigned cum0 = part[t];
  if (K_A >= cum0 && K_A < cum0 + s) {
    unsigned c2 = cum0;
    for (int j = 0; j < 64; ++j) {
      const unsigned c = hb[t*64 + j];
      if (K_A < c2 + c) {
        const unsigned binA = t*64 + j;
        const unsigned residA = K_A - c2;
        unsigned binB, residB;
        if (residA + 1 < c) { binB = binA; residB = residA + 1; }
        else {
          unsigned bb = binA + 1;
          while (bb < 16384 && hb[bb] == 0) ++bb;
          if (bb >= 16384) bb = 16383;  // defensive
          binB = bb; residB = 0;
        }
        out[0] = binA; out[1] = residA; out[2] = binB; out[3] = residB;
        break;
      }
      c2 += c;
    }
  }
  __syncthreads();
  if (t < 4) state[hh*4 + t] = out[t];
}

// full read: compact sortkeys in bins A/B (two-phase LDS reservation, round-5 pattern)
__global__ __launch_bounds__(512) void compact14(const float* __restrict__ scores,
                                                 const unsigned* __restrict__ state,
                                                 unsigned* __restrict__ cand,
                                                 unsigned* __restrict__ ccnt)
{
  const int hh = blockIdx.y;
  __shared__ unsigned lbuf[LCAP];
  __shared__ unsigned lcnt, gbase;
  const int t = threadIdx.x;
  if (t == 0) lcnt = 0;
  __syncthreads();
  const unsigned binA = state[hh*4+0];
  const unsigned binB = state[hh*4+2];
  unsigned* __restrict__ mycand = cand + (size_t)hh * CAPC;
  const float4* base = (const float4*)(scores + (size_t)hh * SS * SS)
                       + (size_t)blockIdx.x * 16384;
  for (int i = t; i < 16384; i += 512) {
    float4 v = base[i];
#pragma unroll
    for (int e = 0; e < 4; ++e) {
      const float f = (e == 0) ? v.x : (e == 1) ? v.y : (e == 2) ? v.z : v.w;
      const unsigned u = sortkey(f);
      const unsigned bin = u >> 18;
      if (bin == binA || bin == binB) {
        unsigned id = atomicAdd(&lcnt, 1u);
        if (id < LCAP) lbuf[id] = u;
        else { unsigned g = atomicAdd(&ccnt[hh], 1u); if (g < CAPC) mycand[g] = u; }
      }
    }
  }
  __syncthreads();
  const unsigned n = (lcnt < LCAP) ? lcnt : LCAP;
  if (t == 0) gbase = n ? atomicAdd(&ccnt[hh], n) : 0u;
  __syncthreads();
  const unsigned gb = gbase;
  for (unsigned i = t; i < n; i += 512)
    if (gb + i < CAPC) mycand[gb + i] = lbuf[i];
}

// resolve remaining 18 bits (8+8+2) from the candidate list; histogram order-invariant
__global__ __launch_bounds__(256) void final_select_list(const unsigned* __restrict__ cand,
                                                         const unsigned* __restrict__ ccnt,
                                                         const unsigned* __restrict__ state,
                                                         float* __restrict__ thr)
{
  const int hh = blockIdx.x;
  const int t = threadIdx.x;
  __shared__ unsigned hist[256];
  __shared__ unsigned digitS, kresS;
  __shared__ float valS[2];
  unsigned n = ccnt[hh]; if (n > CAPC) n = CAPC;
  const unsigned* __restrict__ list = cand + (size_t)hh * CAPC;
  for (int tgt = 0; tgt < 2; ++tgt) {
    unsigned pfx = state[hh*4 + tgt*2];      // 14-bit bin id
    unsigned k   = state[hh*4 + tgt*2 + 1];  // residual rank within bin
    for (int r = 0; r < 3; ++r) {
      const int s = (r == 0) ? 10 : (r == 1) ? 2 : 0;
      const int w = (r == 2) ? 2 : 8;
      const unsigned nb = 1u << w;
      hist[t] = 0;
      __syncthreads();
      for (unsigned i = t; i < n; i += 256) {
        const unsigned u = list[i];
        if ((u >> (s + w)) == pfx) atomicAdd(&hist[(u >> s) & (nb - 1)], 1u);
      }
      __syncthreads();
      if (t == 0) {
        unsigned cum = 0, b = 0;
        for (; b < nb; ++b) { const unsigned c = hist[b]; if (cum + c > k) break; cum += c; }
        if (b == nb) b = nb - 1;
        digitS = b; kresS = k - cum;
      }
      __syncthreads();
      pfx = (pfx << w) | digitS;
      k = kresS;
    }
    if (t == 0) valS[tgt] = inv_sortkey(pfx);
    __syncthreads();
  }
  if (t == 0) thr[hh] = valS[0] + QFRAC * (valS[1] - valS[0]);
}

// ---------------- wave-per-row masked softmax + ballot-compacted sparse PV ----------------
__global__ __launch_bounds__(256) void softmax_pv2(const float* __restrict__ scores,
                                                   const float* __restrict__ thrArr,
                                                   const float* __restrict__ V,
                                                   float* __restrict__ ctx,
                                                   int h0)
{
  const int wave = threadIdx.x >> 6;
  const int lane = threadIdx.x & 63;
  const int row  = blockIdx.x * 4 + wave;
  const int hh   = blockIdx.y;
  const int h    = h0 + hh;
  const float thr = thrArr[hh];
  const float* __restrict__ srow = scores + ((size_t)hh * SS + row) * SS;

  float p[32];
#pragma unroll
  for (int t = 0; t < 32; ++t) p[t] = srow[t*64 + lane];

  float m = -INFINITY;
#pragma unroll
  for (int t = 0; t < 32; ++t)
    if (p[t] >= thr) m = fmaxf(m, p[t]);
#pragma unroll
  for (int off = 32; off; off >>= 1) m = fmaxf(m, __shfl_xor(m, off));

  float sum = 0.f;
#pragma unroll
  for (int t = 0; t < 32; ++t) {
    float e = (p[t] >= thr) ? __expf(p[t] - m) : 0.f;
    p[t] = e;
    sum += e;
  }
#pragma unroll
  for (int off = 32; off; off >>= 1) sum += __shfl_xor(sum, off);

  float acc0 = 0.f, acc1 = 0.f;
  const float* __restrict__ vcol = V + h*64 + lane;
#pragma unroll
  for (int t = 0; t < 32; ++t) {
    unsigned long long mk = __ballot(p[t] != 0.f);
    const float* __restrict__ vt = vcol + (size_t)t * 64 * 1024;
    while (mk) {
      int b0 = __ffsll(mk) - 1; mk &= mk - 1;
      if (mk) {
        int b1 = __ffsll(mk) - 1; mk &= mk - 1;
        float va = vt[(size_t)b0 * 1024];
        float vb = vt[(size_t)b1 * 1024];
        acc0 = fmaf(__shfl(p[t], b0), va, acc0);
        acc1 = fmaf(__shfl(p[t], b1), vb, acc1);
      } else {
        acc0 = fmaf(__shfl(p[t], b0), vt[(size_t)b0 * 1024], acc0);
      }
    }
  }
  ctx[(size_t)row * 1024 + h*64 + lane] = (acc0 + acc1) / sum;
}

// ---------------- host ----------------
extern "C" void kernel_launch(void* const* d_in, const int* in_sizes, int n_in,
                              void* d_out, int out_size, void* d_ws, size_t ws_size,
                              hipStream_t stream)
{
  const float* x  = (const float*)d_in[0];
  const float* Wq = (const float*)d_in[1];
  const float* bq = (const float*)d_in[2];
  const float* Wk = (const float*)d_in[3];
  const float* bk = (const float*)d_in[4];
  const float* Wv = (const float*)d_in[5];
  const float* bv = (const float*)d_in[6];
  const float* Wo = (const float*)d_in[7];
  const float* bo = (const float*)d_in[8];
  float* out = (float*)d_out;
  char*  ws  = (char*)d_ws;

  const size_t SD = (size_t)SS * DD * sizeof(float);  // 8 MiB
  float*    Q     = (float*)(ws + 0*SD);
  float*    K     = (float*)(ws + 1*SD);
  float*    V     = (float*)(ws + 2*SD);
  float*    ctx   = (float*)(ws + 3*SD);
  unsigned* state = (unsigned*)(ws + 4*SD);
  float*    thr   = (float*)(ws + 4*SD + 4096);
  unsigned* ccnt  = (unsigned*)(ws + 4*SD + 8192);
  unsigned* ghist = (unsigned*)(ws + 4*SD + 16384);           // HH*16384*4 = 1 MiB
  unsigned* cand  = (unsigned*)(ws + 4*SD + 16384 + 1048576); // HH*CAPC*4 = 3 MiB
  const size_t off_scores = 4*SD + 16384 + 1048576 + (size_t)HH * CAPC * 4;
  float* scores = (float*)(ws + off_scores);
  const size_t perHead = (size_t)SS * SS * sizeof(float);  // 16 MiB

  int CH = 1;
  if (ws_size > off_scores + perHead)
    CH = (int)((ws_size - off_scores) / perHead);
  if (CH > HH) CH = HH;
  if (CH < 1)  CH = 1;

  gemm_qkv<<<dim3(8, 32, 3), 256, 0, stream>>>(x, Wq, bq, Wk, bk, Wv, bv, Q, K, V);

  for (int h0 = 0; h0 < HH; h0 += CH) {
    const int cnt = (HH - h0 < CH) ? (HH - h0) : CH;
    scores_kernel<<<dim3(16, 16, cnt), 256, 0, stream>>>(Q, K, scores, h0);
    init14<<<256, 256, 0, stream>>>(ghist, ccnt);
    hist14<<<dim3(64, cnt), 512, 0, stream>>>(scores, ghist);
    scan14<<<cnt, 256, 0, stream>>>(ghist, state);
    compact14<<<dim3(64, cnt), 512, 0, stream>>>(scores, state, cand, ccnt);
    final_select_list<<<cnt, 256, 0, stream>>>(cand, ccnt, state, thr);
    softmax_pv2<<<dim3(SS/4, cnt), 256, 0, stream>>>(scores, thr, V, ctx, h0);
  }

  gemm_single<<<dim3(16, 32), 256, 0, stream>>>(ctx, Wo, bo, out);
}

// Round 9
// 782.338 us; speedup vs baseline: 2.2104x; 1.0483x over previous
//
#include <hip/hip_runtime.h>
#include <math.h>

#define SS 2048
#define DD 1024
#define HH 16
#define CAPC 49152u   // candidate slots per head (expected ~22K at 14-bit bins)
#define LCAP 2048     // per-block LDS candidate buffer (expected ~350/block)

// quantile index: floor(0.95*(S*S-1)) = floor(3984587.85)
#define K_A 3984587u
#define K_B 3984588u
#define QFRAC 0.85f

typedef _Float16 f16x8 __attribute__((ext_vector_type(8)));
typedef _Float16 f16x4 __attribute__((ext_vector_type(4)));
typedef float    f32x4 __attribute__((ext_vector_type(4)));

__device__ __forceinline__ unsigned sortkey(float f) {
  unsigned b = __float_as_uint(f);
  return (b & 0x80000000u) ? ~b : (b | 0x80000000u);
}
__device__ __forceinline__ float inv_sortkey(unsigned u) {
  unsigned b = (u & 0x80000000u) ? (u ^ 0x80000000u) : ~u;
  return __uint_as_float(b);
}

// ---------------- fp32 GEMM 64x64 (kept for gemm_single) ----------------
__device__ __forceinline__ void gemm64(const float* __restrict__ A,
                                       const float* __restrict__ B,
                                       const float* __restrict__ bias,
                                       float* __restrict__ C,
                                       int bm, int bn)
{
  __shared__ float As[16][68];
  __shared__ float Bs[16][68];
  const int t  = threadIdx.x;
  const int tx = t & 15, ty = t >> 4;
  const int m0 = bm * 64, n0 = bn * 64;

  float acc[4][4];
#pragma unroll
  for (int i = 0; i < 4; ++i)
#pragma unroll
    for (int j = 0; j < 4; ++j) acc[i][j] = 0.f;

  const int ar = t >> 2;
  const int ak = (t & 3) * 4;
  const int br = t >> 4;
  const int bc = (t & 15) * 4;

  for (int kb = 0; kb < 1024; kb += 16) {
    float4 a0 = *(const float4*)&A[(size_t)(m0 + ar) * 1024 + kb + ak];
    float4 b0 = *(const float4*)&B[(size_t)(kb + br) * 1024 + n0 + bc];
    __syncthreads();
    As[ak+0][ar] = a0.x; As[ak+1][ar] = a0.y; As[ak+2][ar] = a0.z; As[ak+3][ar] = a0.w;
    *(float4*)&Bs[br][bc] = b0;
    __syncthreads();
#pragma unroll
    for (int k = 0; k < 16; ++k) {
      float4 av = *(const float4*)&As[k][ty*4];
      float4 bv = *(const float4*)&Bs[k][tx*4];
      acc[0][0] = fmaf(av.x, bv.x, acc[0][0]); acc[0][1] = fmaf(av.x, bv.y, acc[0][1]);
      acc[0][2] = fmaf(av.x, bv.z, acc[0][2]); acc[0][3] = fmaf(av.x, bv.w, acc[0][3]);
      acc[1][0] = fmaf(av.y, bv.x, acc[1][0]); acc[1][1] = fmaf(av.y, bv.y, acc[1][1]);
      acc[1][2] = fmaf(av.y, bv.z, acc[1][2]); acc[1][3] = fmaf(av.y, bv.w, acc[1][3]);
      acc[2][0] = fmaf(av.z, bv.x, acc[2][0]); acc[2][1] = fmaf(av.z, bv.y, acc[2][1]);
      acc[2][2] = fmaf(av.z, bv.z, acc[2][2]); acc[2][3] = fmaf(av.z, bv.w, acc[2][3]);
      acc[3][0] = fmaf(av.w, bv.x, acc[3][0]); acc[3][1] = fmaf(av.w, bv.y, acc[3][1]);
      acc[3][2] = fmaf(av.w, bv.z, acc[3][2]); acc[3][3] = fmaf(av.w, bv.w, acc[3][3]);
    }
  }
#pragma unroll
  for (int i = 0; i < 4; ++i) {
    const int row = m0 + ty*4 + i;
    const int col = n0 + tx*4;
    float4 o;
    o.x = acc[i][0] + bias[col+0];
    o.y = acc[i][1] + bias[col+1];
    o.z = acc[i][2] + bias[col+2];
    o.w = acc[i][3] + bias[col+3];
    *(float4*)&C[(size_t)row * 1024 + col] = o;
  }
}

// ---------------- fp32 GEMM 64x128 (qkv) with split-fp16 or fp32 epilogue ----------------
// mode 0/1: write hi/lo fp16 split of the fp32 result (Q,K for MFMA scores).
//           fp16 2-term split residual = |lo_err| <= 2^-22 |x| (bf16's 2^-18 failed r8).
// mode 2:   write fp32 (V). fp32 values computed identically to round 7.
__device__ __forceinline__ void gemm64x128_split(const float* __restrict__ A,
                                                 const float* __restrict__ B,
                                                 const float* __restrict__ bias,
                                                 _Float16* __restrict__ Oh,
                                                 _Float16* __restrict__ Ol,
                                                 float* __restrict__ Of,
                                                 int mode, int bm, int bn)
{
  __shared__ float As[16][68];
  __shared__ float Bs[16][132];
  const int t  = threadIdx.x;
  const int tx = t & 15, ty = t >> 4;
  const int m0 = bm * 64, n0 = bn * 128;

  float acc[4][8];
#pragma unroll
  for (int i = 0; i < 4; ++i)
#pragma unroll
    for (int j = 0; j < 8; ++j) acc[i][j] = 0.f;

  const int ar = t >> 2;
  const int ak = (t & 3) * 4;
  const int br = t >> 4;
  const int bc = (t & 15) * 4;    // split columns: bc and 64+bc (2-way bank aliasing, free)

  for (int kb = 0; kb < 1024; kb += 16) {
    float4 a0 = *(const float4*)&A[(size_t)(m0 + ar) * 1024 + kb + ak];
    float4 b0 = *(const float4*)&B[(size_t)(kb + br) * 1024 + n0 + bc];
    float4 b1 = *(const float4*)&B[(size_t)(kb + br) * 1024 + n0 + 64 + bc];
    __syncthreads();
    As[ak+0][ar] = a0.x; As[ak+1][ar] = a0.y; As[ak+2][ar] = a0.z; As[ak+3][ar] = a0.w;
    *(float4*)&Bs[br][bc]      = b0;
    *(float4*)&Bs[br][64 + bc] = b1;
    __syncthreads();
#pragma unroll
    for (int k = 0; k < 16; ++k) {
      float4 av  = *(const float4*)&As[k][ty*4];
      float4 bv0 = *(const float4*)&Bs[k][bc];
      float4 bv1 = *(const float4*)&Bs[k][64 + bc];
      float a4[4]; a4[0]=av.x; a4[1]=av.y; a4[2]=av.z; a4[3]=av.w;
#pragma unroll
      for (int i = 0; i < 4; ++i) {
        acc[i][0] = fmaf(a4[i], bv0.x, acc[i][0]);
        acc[i][1] = fmaf(a4[i], bv0.y, acc[i][1]);
        acc[i][2] = fmaf(a4[i], bv0.z, acc[i][2]);
        acc[i][3] = fmaf(a4[i], bv0.w, acc[i][3]);
        acc[i][4] = fmaf(a4[i], bv1.x, acc[i][4]);
        acc[i][5] = fmaf(a4[i], bv1.y, acc[i][5]);
        acc[i][6] = fmaf(a4[i], bv1.z, acc[i][6]);
        acc[i][7] = fmaf(a4[i], bv1.w, acc[i][7]);
      }
    }
  }
#pragma unroll
  for (int i = 0; i < 4; ++i) {
    const int row = m0 + ty*4 + i;
    const int c0 = n0 + tx*4;
    const int c1 = n0 + 64 + tx*4;
    float o[8];
#pragma unroll
    for (int j = 0; j < 4; ++j) o[j]     = acc[i][j]   + bias[c0+j];
#pragma unroll
    for (int j = 0; j < 4; ++j) o[4+j]   = acc[i][4+j] + bias[c1+j];
    if (mode == 2) {
      *(float4*)&Of[(size_t)row * 1024 + c0] = *(float4*)&o[0];
      *(float4*)&Of[(size_t)row * 1024 + c1] = *(float4*)&o[4];
    } else {
      f16x4 h0, h1, l0, l1;
#pragma unroll
      for (int j = 0; j < 4; ++j) {
        _Float16 h = (_Float16)o[j];
        h0[j] = h;
        l0[j] = (_Float16)(o[j] - (float)h);
      }
#pragma unroll
      for (int j = 0; j < 4; ++j) {
        _Float16 h = (_Float16)o[4+j];
        h1[j] = h;
        l1[j] = (_Float16)(o[4+j] - (float)h);
      }
      *(f16x4*)&Oh[(size_t)row * 1024 + c0] = h0;
      *(f16x4*)&Oh[(size_t)row * 1024 + c1] = h1;
      *(f16x4*)&Ol[(size_t)row * 1024 + c0] = l0;
      *(f16x4*)&Ol[(size_t)row * 1024 + c1] = l1;
    }
  }
}

__global__ __launch_bounds__(256) void gemm_qkv(const float* __restrict__ x,
    const float* __restrict__ Wq, const float* __restrict__ bq,
    const float* __restrict__ Wk, const float* __restrict__ bk,
    const float* __restrict__ Wv, const float* __restrict__ bv,
    _Float16* __restrict__ Qh, _Float16* __restrict__ Ql,
    _Float16* __restrict__ Kh, _Float16* __restrict__ Kl,
    float* __restrict__ V)
{
  const int z = blockIdx.z;
  const float* W = (z == 0) ? Wq : (z == 1) ? Wk : Wv;
  const float* b = (z == 0) ? bq : (z == 1) ? bk : bv;
  _Float16* Oh = (z == 0) ? Qh : Kh;
  _Float16* Ol = (z == 0) ? Ql : Kl;
  gemm64x128_split(x, W, b, Oh, Ol, V, z, blockIdx.y, blockIdx.x);
}

__global__ __launch_bounds__(256) void gemm_single(const float* __restrict__ A,
    const float* __restrict__ W, const float* __restrict__ b, float* __restrict__ O)
{
  gemm64(A, W, b, O, blockIdx.y, blockIdx.x);
}

// ---------------- scores via 4-term split-fp16 MFMA ----------------
// S = Q.K^T/8 with Q=Qh+Ql, K=Kh+Kl (fp16 splits; residual |aL*bL| <= 2^-22|a||b|,
// same class as np's own fp32 rounding). Accumulate LL, HL, LH, HH (small->large).
// 4 waves, each owns a 64x64 quadrant; fragments straight from global (L2-resident);
// no LDS, no barriers. C-layout (m89, dtype-independent): col=lane&15, row=(lane>>4)*4+reg.
__global__ __launch_bounds__(256) void scores_mfma(const _Float16* __restrict__ Qh,
                                                   const _Float16* __restrict__ Ql,
                                                   const _Float16* __restrict__ Kh,
                                                   const _Float16* __restrict__ Kl,
                                                   float* __restrict__ scores,
                                                   int h0)
{
  const int bn = blockIdx.x, bm = blockIdx.y, hh = blockIdx.z;
  const int h = h0 + hh;
  const int wave = threadIdx.x >> 6, lane = threadIdx.x & 63;
  const int wr = wave >> 1, wc = wave & 1;
  const int m0 = bm * 128 + wr * 64;
  const int n0 = bn * 128 + wc * 64;
  const int lr = lane & 15;      // fragment row (A) / row of K (B)
  const int ko = lane >> 4;      // k-subchunk 0..3 (8 fp16 each)

  f32x4 acc[4][4];
#pragma unroll
  for (int i = 0; i < 4; ++i)
#pragma unroll
    for (int j = 0; j < 4; ++j) acc[i][j] = (f32x4){0.f, 0.f, 0.f, 0.f};

#pragma unroll
  for (int kk = 0; kk < 2; ++kk) {
    f16x8 aH[4], aL[4], bH[4], bL[4];
#pragma unroll
    for (int i = 0; i < 4; ++i) {
      const size_t aoff = (size_t)(m0 + i*16 + lr) * 1024 + h*64 + kk*32 + ko*8;
      aH[i] = *(const f16x8*)(Qh + aoff);
      aL[i] = *(const f16x8*)(Ql + aoff);
      const size_t boff = (size_t)(n0 + i*16 + lr) * 1024 + h*64 + kk*32 + ko*8;
      bH[i] = *(const f16x8*)(Kh + boff);
      bL[i] = *(const f16x8*)(Kl + boff);
    }
#pragma unroll
    for (int i = 0; i < 4; ++i)
#pragma unroll
      for (int j = 0; j < 4; ++j) {
        acc[i][j] = __builtin_amdgcn_mfma_f32_16x16x32_f16(aL[i], bL[j], acc[i][j], 0, 0, 0);
        acc[i][j] = __builtin_amdgcn_mfma_f32_16x16x32_f16(aH[i], bL[j], acc[i][j], 0, 0, 0);
        acc[i][j] = __builtin_amdgcn_mfma_f32_16x16x32_f16(aL[i], bH[j], acc[i][j], 0, 0, 0);
        acc[i][j] = __builtin_amdgcn_mfma_f32_16x16x32_f16(aH[i], bH[j], acc[i][j], 0, 0, 0);
      }
  }

#pragma unroll
  for (int i = 0; i < 4; ++i) {
#pragma unroll
    for (int j = 0; j < 4; ++j) {
#pragma unroll
      for (int r = 0; r < 4; ++r) {
        const int row = m0 + i*16 + ko*4 + r;
        const int col = n0 + j*16 + lr;
        scores[((size_t)hh * SS + row) * SS + col] = acc[i][j][r] * 0.125f;
      }
    }
  }
}

// ---------------- radix select, 14-bit first digit ----------------
__global__ __launch_bounds__(256) void init14(unsigned* __restrict__ ghist,
                                              unsigned* __restrict__ ccnt)
{
  int i = blockIdx.x * 256 + threadIdx.x;
  for (; i < HH * 16384; i += gridDim.x * 256) ghist[i] = 0;
  if (blockIdx.x == 0 && threadIdx.x < HH) ccnt[threadIdx.x] = 0;
}

// full read: 16384-bin LDS histogram of sortkey>>18, flushed to global per head
__global__ __launch_bounds__(512) void hist14(const float* __restrict__ scores,
                                              unsigned* __restrict__ ghist)
{
  const int hh = blockIdx.y;
  __shared__ unsigned lh[16384];   // 64 KB
  const int t = threadIdx.x;
  for (int i = t; i < 16384; i += 512) lh[i] = 0;
  __syncthreads();
  const float4* base = (const float4*)(scores + (size_t)hh * SS * SS)
                       + (size_t)blockIdx.x * 16384;
  for (int i = t; i < 16384; i += 512) {
    float4 v = base[i];
    atomicAdd(&lh[sortkey(v.x) >> 18], 1u);
    atomicAdd(&lh[sortkey(v.y) >> 18], 1u);
    atomicAdd(&lh[sortkey(v.z) >> 18], 1u);
    atomicAdd(&lh[sortkey(v.w) >> 18], 1u);
  }
  __syncthreads();
  unsigned* __restrict__ gh = ghist + (size_t)hh * 16384;
  for (int i = t; i < 16384; i += 512) {
    const unsigned c = lh[i];
    if (c) atomicAdd(&gh[i], c);
  }
}

// find the 14-bit bins holding ranks K_A and K_B=K_A+1 (O(1) second-bin rule)
__global__ __launch_bounds__(256) void scan14(const unsigned* __restrict__ ghist,
                                              unsigned* __restrict__ state)
{
  const int hh = blockIdx.x;
  const int t = threadIdx.x;
  __shared__ unsigned part[256];
  __shared__ unsigned out[4];
  const unsigned* __restrict__ hb = ghist + (size_t)hh * 16384;
  unsigned s = 0;
  for (int j = 0; j < 64; ++j) s += hb[t*64 + j];
  part[t] = s;
  __syncthreads();
  if (t == 0) {
    unsigned run = 0;
    for (int i = 0; i < 256; ++i) { unsigned tmp = part[i]; part[i] = run; run += tmp; }
  }
  __syncthreads();
  const unsigned cum0 = part[t];
  if (K_A >= cum0 && K_A < cum0 + s) {
    unsigned c2 = cum0;
    for (int j = 0; j < 64; ++j) {
      const unsigned c = hb[t*64 + j];
      if (K_A < c2 + c) {
        const unsigned binA = t*64 + j;
        const unsigned residA = K_A - c2;
        unsigned binB, residB;
        if (residA + 1 < c) { binB = binA; residB = residA + 1; }
        else {
          unsigned bb = binA + 1;
          while (bb < 16384 && hb[bb] == 0) ++bb;
          if (bb >= 16384) bb = 16383;  // defensive
          binB = bb; residB = 0;
        }
        out[0] = binA; out[1] = residA; out[2] = binB; out[3] = residB;
        break;
      }
      c2 += c;
    }
  }
  __syncthreads();
  if (t < 4) state[hh*4 + t] = out[t];
}

// full read: compact sortkeys in bins A/B (two-phase LDS reservation, round-5 pattern)
__global__ __launch_bounds__(512) void compact14(const float* __restrict__ scores,
                                                 const unsigned* __restrict__ state,
                                                 unsigned* __restrict__ cand,
                                                 unsigned* __restrict__ ccnt)
{
  const int hh = blockIdx.y;
  __shared__ unsigned lbuf[LCAP];
  __shared__ unsigned lcnt, gbase;
  const int t = threadIdx.x;
  if (t == 0) lcnt = 0;
  __syncthreads();
  const unsigned binA = state[hh*4+0];
  const unsigned binB = state[hh*4+2];
  unsigned* __restrict__ mycand = cand + (size_t)hh * CAPC;
  const float4* base = (const float4*)(scores + (size_t)hh * SS * SS)
                       + (size_t)blockIdx.x * 16384;
  for (int i = t; i < 16384; i += 512) {
    float4 v = base[i];
#pragma unroll
    for (int e = 0; e < 4; ++e) {
      const float f = (e == 0) ? v.x : (e == 1) ? v.y : (e == 2) ? v.z : v.w;
      const unsigned u = sortkey(f);
      const unsigned bin = u >> 18;
      if (bin == binA || bin == binB) {
        unsigned id = atomicAdd(&lcnt, 1u);
        if (id < LCAP) lbuf[id] = u;
        else { unsigned g = atomicAdd(&ccnt[hh], 1u); if (g < CAPC) mycand[g] = u; }
      }
    }
  }
  __syncthreads();
  const unsigned n = (lcnt < LCAP) ? lcnt : LCAP;
  if (t == 0) gbase = n ? atomicAdd(&ccnt[hh], n) : 0u;
  __syncthreads();
  const unsigned gb = gbase;
  for (unsigned i = t; i < n; i += 512)
    if (gb + i < CAPC) mycand[gb + i] = lbuf[i];
}

// resolve remaining 18 bits (8+8+2) from the candidate list; histogram order-invariant
__global__ __launch_bounds__(256) void final_select_list(const unsigned* __restrict__ cand,
                                                         const unsigned* __restrict__ ccnt,
                                                         const unsigned* __restrict__ state,
                                                         float* __restrict__ thr)
{
  const int hh = blockIdx.x;
  const int t = threadIdx.x;
  __shared__ unsigned hist[256];
  __shared__ unsigned digitS, kresS;
  __shared__ float valS[2];
  unsigned n = ccnt[hh]; if (n > CAPC) n = CAPC;
  const unsigned* __restrict__ list = cand + (size_t)hh * CAPC;
  for (int tgt = 0; tgt < 2; ++tgt) {
    unsigned pfx = state[hh*4 + tgt*2];      // 14-bit bin id
    unsigned k   = state[hh*4 + tgt*2 + 1];  // residual rank within bin
    for (int r = 0; r < 3; ++r) {
      const int s = (r == 0) ? 10 : (r == 1) ? 2 : 0;
      const int w = (r == 2) ? 2 : 8;
      const unsigned nb = 1u << w;
      hist[t] = 0;
      __syncthreads();
      for (unsigned i = t; i < n; i += 256) {
        const unsigned u = list[i];
        if ((u >> (s + w)) == pfx) atomicAdd(&hist[(u >> s) & (nb - 1)], 1u);
      }
      __syncthreads();
      if (t == 0) {
        unsigned cum = 0, b = 0;
        for (; b < nb; ++b) { const unsigned c = hist[b]; if (cum + c > k) break; cum += c; }
        if (b == nb) b = nb - 1;
        digitS = b; kresS = k - cum;
      }
      __syncthreads();
      pfx = (pfx << w) | digitS;
      k = kresS;
    }
    if (t == 0) valS[tgt] = inv_sortkey(pfx);
    __syncthreads();
  }
  if (t == 0) thr[hh] = valS[0] + QFRAC * (valS[1] - valS[0]);
}

// ---------------- wave-per-row masked softmax + ballot-compacted sparse PV ----------------
__global__ __launch_bounds__(256) void softmax_pv2(const float* __restrict__ scores,
                                                   const float* __restrict__ thrArr,
                                                   const float* __restrict__ V,
                                                   float* __restrict__ ctx,
                                                   int h0)
{
  const int wave = threadIdx.x >> 6;
  const int lane = threadIdx.x & 63;
  const int row  = blockIdx.x * 4 + wave;
  const int hh   = blockIdx.y;
  const int h    = h0 + hh;
  const float thr = thrArr[hh];
  const float* __restrict__ srow = scores + ((size_t)hh * SS + row) * SS;

  float p[32];
#pragma unroll
  for (int t = 0; t < 32; ++t) p[t] = srow[t*64 + lane];

  float m = -INFINITY;
#pragma unroll
  for (int t = 0; t < 32; ++t)
    if (p[t] >= thr) m = fmaxf(m, p[t]);
#pragma unroll
  for (int off = 32; off; off >>= 1) m = fmaxf(m, __shfl_xor(m, off));

  float sum = 0.f;
#pragma unroll
  for (int t = 0; t < 32; ++t) {
    float e = (p[t] >= thr) ? __expf(p[t] - m) : 0.f;
    p[t] = e;
    sum += e;
  }
#pragma unroll
  for (int off = 32; off; off >>= 1) sum += __shfl_xor(sum, off);

  float acc0 = 0.f, acc1 = 0.f;
  const float* __restrict__ vcol = V + h*64 + lane;
#pragma unroll
  for (int t = 0; t < 32; ++t) {
    unsigned long long mk = __ballot(p[t] != 0.f);
    const float* __restrict__ vt = vcol + (size_t)t * 64 * 1024;
    while (mk) {
      int b0 = __ffsll(mk) - 1; mk &= mk - 1;
      if (mk) {
        int b1 = __ffsll(mk) - 1; mk &= mk - 1;
        float va = vt[(size_t)b0 * 1024];
        float vb = vt[(size_t)b1 * 1024];
        acc0 = fmaf(__shfl(p[t], b0), va, acc0);
        acc1 = fmaf(__shfl(p[t], b1), vb, acc1);
      } else {
        acc0 = fmaf(__shfl(p[t], b0), vt[(size_t)b0 * 1024], acc0);
      }
    }
  }
  ctx[(size_t)row * 1024 + h*64 + lane] = (acc0 + acc1) / sum;
}

// ---------------- host ----------------
extern "C" void kernel_launch(void* const* d_in, const int* in_sizes, int n_in,
                              void* d_out, int out_size, void* d_ws, size_t ws_size,
                              hipStream_t stream)
{
  const float* x  = (const float*)d_in[0];
  const float* Wq = (const float*)d_in[1];
  const float* bq = (const float*)d_in[2];
  const float* Wk = (const float*)d_in[3];
  const float* bk = (const float*)d_in[4];
  const float* Wv = (const float*)d_in[5];
  const float* bv = (const float*)d_in[6];
  const float* Wo = (const float*)d_in[7];
  const float* bo = (const float*)d_in[8];
  float* out = (float*)d_out;
  char*  ws  = (char*)d_ws;

  const size_t HB = (size_t)SS * DD * 2;              // 4 MiB (fp16 plane)
  _Float16* Qh = (_Float16*)(ws + 0*HB);
  _Float16* Ql = (_Float16*)(ws + 1*HB);
  _Float16* Kh = (_Float16*)(ws + 2*HB);
  _Float16* Kl = (_Float16*)(ws + 3*HB);
  float* V   = (float*)(ws + 4*HB);                    // 8 MiB fp32
  float* ctx = (float*)(ws + 4*HB + (size_t)SS*DD*4);
  const size_t base = 4*HB + 2*(size_t)SS*DD*4;        // 32 MiB
  unsigned* state = (unsigned*)(ws + base);
  float*    thr   = (float*)(ws + base + 4096);
  unsigned* ccnt  = (unsigned*)(ws + base + 8192);
  unsigned* ghist = (unsigned*)(ws + base + 16384);            // 1 MiB
  unsigned* cand  = (unsigned*)(ws + base + 16384 + 1048576);  // 3 MiB
  const size_t off_scores = base + 16384 + 1048576 + (size_t)HH * CAPC * 4;
  float* scores = (float*)(ws + off_scores);
  const size_t perHead = (size_t)SS * SS * sizeof(float);  // 16 MiB

  int CH = 1;
  if (ws_size > off_scores + perHead)
    CH = (int)((ws_size - off_scores) / perHead);
  if (CH > HH) CH = HH;
  if (CH < 1)  CH = 1;

  gemm_qkv<<<dim3(8, 32, 3), 256, 0, stream>>>(x, Wq, bq, Wk, bk, Wv, bv,
                                               Qh, Ql, Kh, Kl, V);

  for (int h0 = 0; h0 < HH; h0 += CH) {
    const int cnt = (HH - h0 < CH) ? (HH - h0) : CH;
    scores_mfma<<<dim3(16, 16, cnt), 256, 0, stream>>>(Qh, Ql, Kh, Kl, scores, h0);
    init14<<<256, 256, 0, stream>>>(ghist, ccnt);
    hist14<<<dim3(64, cnt), 512, 0, stream>>>(scores, ghist);
    scan14<<<cnt, 256, 0, stream>>>(ghist, state);
    compact14<<<dim3(64, cnt), 512, 0, stream>>>(scores, state, cand, ccnt);
    final_select_list<<<cnt, 256, 0, stream>>>(cand, ccnt, state, thr);
    softmax_pv2<<<dim3(SS/4, cnt), 256, 0, stream>>>(scores, thr, V, ctx, h0);
  }

  gemm_single<<<dim3(16, 32), 256, 0, stream>>>(ctx, Wo, bo, out);
}

// Round 10
// 742.790 us; speedup vs baseline: 2.3281x; 1.0532x over previous
//
#include <hip/hip_runtime.h>
#include <math.h>

#define SS 2048
#define DD 1024
#define HH 16
#define CAPC 49152u   // candidate slots per head (expected ~22K at 14-bit bins)
#define LCAP 2048     // per-block LDS candidate buffer (expected ~350/block)

// quantile index: floor(0.95*(S*S-1)) = floor(3984587.85)
#define K_A 3984587u
#define K_B 3984588u
#define QFRAC 0.85f
#define WSCALE 2048.0f      // W planes pre-scaled so lo-residuals stay normal fp16
#define WSCALE_INV (1.0f/2048.0f)

typedef _Float16 f16x8 __attribute__((ext_vector_type(8)));
typedef _Float16 f16x4 __attribute__((ext_vector_type(4)));
typedef float    f32x4 __attribute__((ext_vector_type(4)));

__device__ __forceinline__ unsigned sortkey(float f) {
  unsigned b = __float_as_uint(f);
  return (b & 0x80000000u) ? ~b : (b | 0x80000000u);
}
__device__ __forceinline__ float inv_sortkey(unsigned u) {
  unsigned b = (u & 0x80000000u) ? (u ^ 0x80000000u) : ~u;
  return __uint_as_float(b);
}

// ---------------- input splitting ----------------
// x [2048,1024] fp32 -> xh,xl fp16 planes (row-major, unscaled: x~N(0,1),
// lo ~3e-4 mostly normal — the regime round 9 validated on Q/K planes).
__global__ __launch_bounds__(256) void split_x(const float* __restrict__ x,
                                               _Float16* __restrict__ xh,
                                               _Float16* __restrict__ xl)
{
  const int i = blockIdx.x * 256 + threadIdx.x;   // float4 index, 524288 total
  float4 v = ((const float4*)x)[i];
  float vv[4] = {v.x, v.y, v.z, v.w};
  f16x4 h, l;
#pragma unroll
  for (int j = 0; j < 4; ++j) {
    _Float16 hh = (_Float16)vv[j];
    h[j] = hh;
    l[j] = (_Float16)(vv[j] - (float)hh);
  }
  ((f16x4*)xh)[i] = h;
  ((f16x4*)xl)[i] = l;
}

// W [1024,1024] fp32 -> transposed hi/lo fp16 planes WT[n][k], scaled by 2048
// (W~0.02: unscaled lo ~1e-5 would be fp16-subnormal; x2048 -> ~0.02, normal).
// z selects Wq/Wk/Wv/Wo -> plane pairs 0..7 in wplanes.
__global__ __launch_bounds__(256) void split_wT(const float* __restrict__ Wq,
                                                const float* __restrict__ Wk,
                                                const float* __restrict__ Wv,
                                                const float* __restrict__ Wo,
                                                _Float16* __restrict__ wplanes)
{
  const int z = blockIdx.z;
  const float* W = (z == 0) ? Wq : (z == 1) ? Wk : (z == 2) ? Wv : Wo;
  _Float16* WhT = wplanes + (size_t)(2*z)     * (1024*1024);
  _Float16* WlT = wplanes + (size_t)(2*z + 1) * (1024*1024);
  __shared__ float tile[64][65];
  const int t  = threadIdx.x;
  const int r  = t >> 2;         // 0..63
  const int c0 = (t & 3) * 16;   // 0/16/32/48
  const int k0 = blockIdx.y * 64;
  const int n0 = blockIdx.x * 64;
#pragma unroll
  for (int j = 0; j < 4; ++j) {
    float4 v = *(const float4*)&W[(size_t)(k0 + r) * 1024 + n0 + c0 + j*4];
    tile[r][c0+j*4+0] = v.x; tile[r][c0+j*4+1] = v.y;
    tile[r][c0+j*4+2] = v.z; tile[r][c0+j*4+3] = v.w;
  }
  __syncthreads();
  f16x8 h0, h1, l0, l1;
#pragma unroll
  for (int j = 0; j < 8; ++j) {
    float v = tile[c0 + j][r] * WSCALE;
    _Float16 h = (_Float16)v;
    h0[j] = h; l0[j] = (_Float16)(v - (float)h);
  }
#pragma unroll
  for (int j = 0; j < 8; ++j) {
    float v = tile[c0 + 8 + j][r] * WSCALE;
    _Float16 h = (_Float16)v;
    h1[j] = h; l1[j] = (_Float16)(v - (float)h);
  }
  const size_t o = (size_t)(n0 + r) * 1024 + k0 + c0;
  *(f16x8*)&WhT[o]     = h0;
  *(f16x8*)&WhT[o + 8] = h1;
  *(f16x8*)&WlT[o]     = l0;
  *(f16x8*)&WlT[o + 8] = l1;
}

// ---------------- MFMA GEMM: O[2048,1024] = A@B + bias ----------------
// A as (Ah,Al) fp16 planes [M][K]; B as (BhT,BlT) fp16 planes [N][K] (transposed,
// scaled by WSCALE). 4-term split MFMA (LL,HL,LH,HH) accumulated in fp32.
// Structure = round-9-validated scores_mfma: 4 waves x 64x64 quadrants,
// fragments straight from global (L2-resident), no LDS, no barriers.
// C-layout (m89): col=lane&15, row=(lane>>4)*4+reg.
// fp32out=0: epilogue splits result into (Oh,Ol) fp16 planes; =1: fp32 to Of.
__device__ __forceinline__ void gemm_mfma_body(const _Float16* __restrict__ Ah,
                                               const _Float16* __restrict__ Al,
                                               const _Float16* __restrict__ BhT,
                                               const _Float16* __restrict__ BlT,
                                               const float* __restrict__ bias,
                                               _Float16* __restrict__ Oh,
                                               _Float16* __restrict__ Ol,
                                               float* __restrict__ Of,
                                               int fp32out, int bm, int bn)
{
  const int wave = threadIdx.x >> 6, lane = threadIdx.x & 63;
  const int wr = wave >> 1, wc = wave & 1;
  const int m0 = bm * 128 + wr * 64;
  const int n0 = bn * 128 + wc * 64;
  const int lr = lane & 15;
  const int ko = lane >> 4;

  f32x4 acc[4][4];
#pragma unroll
  for (int i = 0; i < 4; ++i)
#pragma unroll
    for (int j = 0; j < 4; ++j) acc[i][j] = (f32x4){0.f, 0.f, 0.f, 0.f};

  for (int kk = 0; kk < 32; ++kk) {
    const int kof = kk*32 + ko*8;
    f16x8 aH[4], aL[4], bH[4], bL[4];
#pragma unroll
    for (int i = 0; i < 4; ++i) {
      const size_t aoff = (size_t)(m0 + i*16 + lr) * 1024 + kof;
      aH[i] = *(const f16x8*)(Ah + aoff);
      aL[i] = *(const f16x8*)(Al + aoff);
      const size_t boff = (size_t)(n0 + i*16 + lr) * 1024 + kof;
      bH[i] = *(const f16x8*)(BhT + boff);
      bL[i] = *(const f16x8*)(BlT + boff);
    }
#pragma unroll
    for (int i = 0; i < 4; ++i)
#pragma unroll
      for (int j = 0; j < 4; ++j) {
        acc[i][j] = __builtin_amdgcn_mfma_f32_16x16x32_f16(aL[i], bL[j], acc[i][j], 0, 0, 0);
        acc[i][j] = __builtin_amdgcn_mfma_f32_16x16x32_f16(aH[i], bL[j], acc[i][j], 0, 0, 0);
        acc[i][j] = __builtin_amdgcn_mfma_f32_16x16x32_f16(aL[i], bH[j], acc[i][j], 0, 0, 0);
        acc[i][j] = __builtin_amdgcn_mfma_f32_16x16x32_f16(aH[i], bH[j], acc[i][j], 0, 0, 0);
      }
  }

#pragma unroll
  for (int i = 0; i < 4; ++i) {
#pragma unroll
    for (int j = 0; j < 4; ++j) {
#pragma unroll
      for (int r = 0; r < 4; ++r) {
        const int row = m0 + i*16 + ko*4 + r;
        const int col = n0 + j*16 + lr;
        const float val = acc[i][j][r] * WSCALE_INV + bias[col];
        if (fp32out) {
          Of[(size_t)row * 1024 + col] = val;
        } else {
          _Float16 h = (_Float16)val;
          Oh[(size_t)row * 1024 + col] = h;
          Ol[(size_t)row * 1024 + col] = (_Float16)(val - (float)h);
        }
      }
    }
  }
}

__global__ __launch_bounds__(256) void gemm_mfma_qkv(const _Float16* __restrict__ xh,
                                                     const _Float16* __restrict__ xl,
                                                     const _Float16* __restrict__ wplanes,
                                                     const float* __restrict__ bq,
                                                     const float* __restrict__ bk,
                                                     const float* __restrict__ bv,
                                                     _Float16* __restrict__ Qh,
                                                     _Float16* __restrict__ Ql,
                                                     _Float16* __restrict__ Kh,
                                                     _Float16* __restrict__ Kl,
                                                     float* __restrict__ V)
{
  const int z = blockIdx.z;
  const _Float16* BhT = wplanes + (size_t)(2*z)     * (1024*1024);
  const _Float16* BlT = wplanes + (size_t)(2*z + 1) * (1024*1024);
  const float* bias = (z == 0) ? bq : (z == 1) ? bk : bv;
  _Float16* Oh = (z == 0) ? Qh : Kh;
  _Float16* Ol = (z == 0) ? Ql : Kl;
  gemm_mfma_body(xh, xl, BhT, BlT, bias, Oh, Ol, V, (z == 2) ? 1 : 0,
                 blockIdx.y, blockIdx.x);
}

__global__ __launch_bounds__(256) void gemm_mfma_o(const _Float16* __restrict__ ctxh,
                                                   const _Float16* __restrict__ ctxl,
                                                   const _Float16* __restrict__ wplanes,
                                                   const float* __restrict__ bo,
                                                   float* __restrict__ out)
{
  gemm_mfma_body(ctxh, ctxl,
                 wplanes + (size_t)6 * (1024*1024),
                 wplanes + (size_t)7 * (1024*1024),
                 bo, nullptr, nullptr, out, 1, blockIdx.y, blockIdx.x);
}

// ---------------- scores via 4-term split-fp16 MFMA (round-9, unchanged) ----------------
__global__ __launch_bounds__(256) void scores_mfma(const _Float16* __restrict__ Qh,
                                                   const _Float16* __restrict__ Ql,
                                                   const _Float16* __restrict__ Kh,
                                                   const _Float16* __restrict__ Kl,
                                                   float* __restrict__ scores,
                                                   int h0)
{
  const int bn = blockIdx.x, bm = blockIdx.y, hh = blockIdx.z;
  const int h = h0 + hh;
  const int wave = threadIdx.x >> 6, lane = threadIdx.x & 63;
  const int wr = wave >> 1, wc = wave & 1;
  const int m0 = bm * 128 + wr * 64;
  const int n0 = bn * 128 + wc * 64;
  const int lr = lane & 15;
  const int ko = lane >> 4;

  f32x4 acc[4][4];
#pragma unroll
  for (int i = 0; i < 4; ++i)
#pragma unroll
    for (int j = 0; j < 4; ++j) acc[i][j] = (f32x4){0.f, 0.f, 0.f, 0.f};

#pragma unroll
  for (int kk = 0; kk < 2; ++kk) {
    f16x8 aH[4], aL[4], bH[4], bL[4];
#pragma unroll
    for (int i = 0; i < 4; ++i) {
      const size_t aoff = (size_t)(m0 + i*16 + lr) * 1024 + h*64 + kk*32 + ko*8;
      aH[i] = *(const f16x8*)(Qh + aoff);
      aL[i] = *(const f16x8*)(Ql + aoff);
      const size_t boff = (size_t)(n0 + i*16 + lr) * 1024 + h*64 + kk*32 + ko*8;
      bH[i] = *(const f16x8*)(Kh + boff);
      bL[i] = *(const f16x8*)(Kl + boff);
    }
#pragma unroll
    for (int i = 0; i < 4; ++i)
#pragma unroll
      for (int j = 0; j < 4; ++j) {
        acc[i][j] = __builtin_amdgcn_mfma_f32_16x16x32_f16(aL[i], bL[j], acc[i][j], 0, 0, 0);
        acc[i][j] = __builtin_amdgcn_mfma_f32_16x16x32_f16(aH[i], bL[j], acc[i][j], 0, 0, 0);
        acc[i][j] = __builtin_amdgcn_mfma_f32_16x16x32_f16(aL[i], bH[j], acc[i][j], 0, 0, 0);
        acc[i][j] = __builtin_amdgcn_mfma_f32_16x16x32_f16(aH[i], bH[j], acc[i][j], 0, 0, 0);
      }
  }

#pragma unroll
  for (int i = 0; i < 4; ++i) {
#pragma unroll
    for (int j = 0; j < 4; ++j) {
#pragma unroll
      for (int r = 0; r < 4; ++r) {
        const int row = m0 + i*16 + ko*4 + r;
        const int col = n0 + j*16 + lr;
        scores[((size_t)hh * SS + row) * SS + col] = acc[i][j][r] * 0.125f;
      }
    }
  }
}

// ---------------- radix select, 14-bit first digit ----------------
__global__ __launch_bounds__(256) void init14(unsigned* __restrict__ ghist,
                                              unsigned* __restrict__ ccnt)
{
  int i = blockIdx.x * 256 + threadIdx.x;
  for (; i < HH * 16384; i += gridDim.x * 256) ghist[i] = 0;
  if (blockIdx.x == 0 && threadIdx.x < HH) ccnt[threadIdx.x] = 0;
}

__global__ __launch_bounds__(512) void hist14(const float* __restrict__ scores,
                                              unsigned* __restrict__ ghist)
{
  const int hh = blockIdx.y;
  __shared__ unsigned lh[16384];   // 64 KB
  const int t = threadIdx.x;
  for (int i = t; i < 16384; i += 512) lh[i] = 0;
  __syncthreads();
  const float4* base = (const float4*)(scores + (size_t)hh * SS * SS)
                       + (size_t)blockIdx.x * 16384;
  for (int i = t; i < 16384; i += 512) {
    float4 v = base[i];
    atomicAdd(&lh[sortkey(v.x) >> 18], 1u);
    atomicAdd(&lh[sortkey(v.y) >> 18], 1u);
    atomicAdd(&lh[sortkey(v.z) >> 18], 1u);
    atomicAdd(&lh[sortkey(v.w) >> 18], 1u);
  }
  __syncthreads();
  unsigned* __restrict__ gh = ghist + (size_t)hh * 16384;
  for (int i = t; i < 16384; i += 512) {
    const unsigned c = lh[i];
    if (c) atomicAdd(&gh[i], c);
  }
}

__global__ __launch_bounds__(256) void scan14(const unsigned* __restrict__ ghist,
                                              unsigned* __restrict__ state)
{
  const int hh = blockIdx.x;
  const int t = threadIdx.x;
  __shared__ unsigned part[256];
  __shared__ unsigned out[4];
  const unsigned* __restrict__ hb = ghist + (size_t)hh * 16384;
  unsigned s = 0;
  for (int j = 0; j < 64; ++j) s += hb[t*64 + j];
  part[t] = s;
  __syncthreads();
  if (t == 0) {
    unsigned run = 0;
    for (int i = 0; i < 256; ++i) { unsigned tmp = part[i]; part[i] = run; run += tmp; }
  }
  __syncthreads();
  const unsigned cum0 = part[t];
  if (K_A >= cum0 && K_A < cum0 + s) {
    unsigned c2 = cum0;
    for (int j = 0; j < 64; ++j) {
      const unsigned c = hb[t*64 + j];
      if (K_A < c2 + c) {
        const unsigned binA = t*64 + j;
        const unsigned residA = K_A - c2;
        unsigned binB, residB;
        if (residA + 1 < c) { binB = binA; residB = residA + 1; }
        else {
          unsigned bb = binA + 1;
          while (bb < 16384 && hb[bb] == 0) ++bb;
          if (bb >= 16384) bb = 16383;  // defensive
          binB = bb; residB = 0;
        }
        out[0] = binA; out[1] = residA; out[2] = binB; out[3] = residB;
        break;
      }
      c2 += c;
    }
  }
  __syncthreads();
  if (t < 4) state[hh*4 + t] = out[t];
}

__global__ __launch_bounds__(512) void compact14(const float* __restrict__ scores,
                                                 const unsigned* __restrict__ state,
                                                 unsigned* __restrict__ cand,
                                                 unsigned* __restrict__ ccnt)
{
  const int hh = blockIdx.y;
  __shared__ unsigned lbuf[LCAP];
  __shared__ unsigned lcnt, gbase;
  const int t = threadIdx.x;
  if (t == 0) lcnt = 0;
  __syncthreads();
  const unsigned binA = state[hh*4+0];
  const unsigned binB = state[hh*4+2];
  unsigned* __restrict__ mycand = cand + (size_t)hh * CAPC;
  const float4* base = (const float4*)(scores + (size_t)hh * SS * SS)
                       + (size_t)blockIdx.x * 16384;
  for (int i = t; i < 16384; i += 512) {
    float4 v = base[i];
#pragma unroll
    for (int e = 0; e < 4; ++e) {
      const float f = (e == 0) ? v.x : (e == 1) ? v.y : (e == 2) ? v.z : v.w;
      const unsigned u = sortkey(f);
      const unsigned bin = u >> 18;
      if (bin == binA || bin == binB) {
        unsigned id = atomicAdd(&lcnt, 1u);
        if (id < LCAP) lbuf[id] = u;
        else { unsigned g = atomicAdd(&ccnt[hh], 1u); if (g < CAPC) mycand[g] = u; }
      }
    }
  }
  __syncthreads();
  const unsigned n = (lcnt < LCAP) ? lcnt : LCAP;
  if (t == 0) gbase = n ? atomicAdd(&ccnt[hh], n) : 0u;
  __syncthreads();
  const unsigned gb = gbase;
  for (unsigned i = t; i < n; i += 512)
    if (gb + i < CAPC) mycand[gb + i] = lbuf[i];
}

__global__ __launch_bounds__(256) void final_select_list(const unsigned* __restrict__ cand,
                                                         const unsigned* __restrict__ ccnt,
                                                         const unsigned* __restrict__ state,
                                                         float* __restrict__ thr)
{
  const int hh = blockIdx.x;
  const int t = threadIdx.x;
  __shared__ unsigned hist[256];
  __shared__ unsigned digitS, kresS;
  __shared__ float valS[2];
  unsigned n = ccnt[hh]; if (n > CAPC) n = CAPC;
  const unsigned* __restrict__ list = cand + (size_t)hh * CAPC;
  for (int tgt = 0; tgt < 2; ++tgt) {
    unsigned pfx = state[hh*4 + tgt*2];
    unsigned k   = state[hh*4 + tgt*2 + 1];
    for (int r = 0; r < 3; ++r) {
      const int s = (r == 0) ? 10 : (r == 1) ? 2 : 0;
      const int w = (r == 2) ? 2 : 8;
      const unsigned nb = 1u << w;
      hist[t] = 0;
      __syncthreads();
      for (unsigned i = t; i < n; i += 256) {
        const unsigned u = list[i];
        if ((u >> (s + w)) == pfx) atomicAdd(&hist[(u >> s) & (nb - 1)], 1u);
      }
      __syncthreads();
      if (t == 0) {
        unsigned cum = 0, b = 0;
        for (; b < nb; ++b) { const unsigned c = hist[b]; if (cum + c > k) break; cum += c; }
        if (b == nb) b = nb - 1;
        digitS = b; kresS = k - cum;
      }
      __syncthreads();
      pfx = (pfx << w) | digitS;
      k = kresS;
    }
    if (t == 0) valS[tgt] = inv_sortkey(pfx);
    __syncthreads();
  }
  if (t == 0) thr[hh] = valS[0] + QFRAC * (valS[1] - valS[0]);
}

// ---------------- wave-per-row masked softmax + ballot-compacted sparse PV ----------------
// Epilogue now writes ctx as fp16 hi/lo planes (feeds the MFMA output GEMM).
__global__ __launch_bounds__(256) void softmax_pv2(const float* __restrict__ scores,
                                                   const float* __restrict__ thrArr,
                                                   const float* __restrict__ V,
                                                   _Float16* __restrict__ ctxh,
                                                   _Float16* __restrict__ ctxl,
                                                   int h0)
{
  const int wave = threadIdx.x >> 6;
  const int lane = threadIdx.x & 63;
  const int row  = blockIdx.x * 4 + wave;
  const int hh   = blockIdx.y;
  const int h    = h0 + hh;
  const float thr = thrArr[hh];
  const float* __restrict__ srow = scores + ((size_t)hh * SS + row) * SS;

  float p[32];
#pragma unroll
  for (int t = 0; t < 32; ++t) p[t] = srow[t*64 + lane];

  float m = -INFINITY;
#pragma unroll
  for (int t = 0; t < 32; ++t)
    if (p[t] >= thr) m = fmaxf(m, p[t]);
#pragma unroll
  for (int off = 32; off; off >>= 1) m = fmaxf(m, __shfl_xor(m, off));

  float sum = 0.f;
#pragma unroll
  for (int t = 0; t < 32; ++t) {
    float e = (p[t] >= thr) ? __expf(p[t] - m) : 0.f;
    p[t] = e;
    sum += e;
  }
#pragma unroll
  for (int off = 32; off; off >>= 1) sum += __shfl_xor(sum, off);

  float acc0 = 0.f, acc1 = 0.f;
  const float* __restrict__ vcol = V + h*64 + lane;
#pragma unroll
  for (int t = 0; t < 32; ++t) {
    unsigned long long mk = __ballot(p[t] != 0.f);
    const float* __restrict__ vt = vcol + (size_t)t * 64 * 1024;
    while (mk) {
      int b0 = __ffsll(mk) - 1; mk &= mk - 1;
      if (mk) {
        int b1 = __ffsll(mk) - 1; mk &= mk - 1;
        float va = vt[(size_t)b0 * 1024];
        float vb = vt[(size_t)b1 * 1024];
        acc0 = fmaf(__shfl(p[t], b0), va, acc0);
        acc1 = fmaf(__shfl(p[t], b1), vb, acc1);
      } else {
        acc0 = fmaf(__shfl(p[t], b0), vt[(size_t)b0 * 1024], acc0);
      }
    }
  }
  const float val = (acc0 + acc1) / sum;
  const size_t oidx = (size_t)row * 1024 + h*64 + lane;
  _Float16 hv = (_Float16)val;
  ctxh[oidx] = hv;
  ctxl[oidx] = (_Float16)(val - (float)hv);
}

// ---------------- host ----------------
extern "C" void kernel_launch(void* const* d_in, const int* in_sizes, int n_in,
                              void* d_out, int out_size, void* d_ws, size_t ws_size,
                              hipStream_t stream)
{
  const float* x  = (const float*)d_in[0];
  const float* Wq = (const float*)d_in[1];
  const float* bq = (const float*)d_in[2];
  const float* Wk = (const float*)d_in[3];
  const float* bk = (const float*)d_in[4];
  const float* Wv = (const float*)d_in[5];
  const float* bv = (const float*)d_in[6];
  const float* Wo = (const float*)d_in[7];
  const float* bo = (const float*)d_in[8];
  float* out = (float*)d_out;
  char*  ws  = (char*)d_ws;

  const size_t MB = 1u << 20;
  _Float16* xh      = (_Float16*)(ws + 0*MB);    // 4 MiB each fp16 plane
  _Float16* xl      = (_Float16*)(ws + 4*MB);
  _Float16* wplanes = (_Float16*)(ws + 8*MB);    // 8 x 2 MiB transposed W planes
  _Float16* Qh      = (_Float16*)(ws + 24*MB);
  _Float16* Ql      = (_Float16*)(ws + 28*MB);
  _Float16* Kh      = (_Float16*)(ws + 32*MB);
  _Float16* Kl      = (_Float16*)(ws + 36*MB);
  float*    V       = (float*)   (ws + 40*MB);   // 8 MiB fp32
  _Float16* ctxh    = (_Float16*)(ws + 48*MB);
  _Float16* ctxl    = (_Float16*)(ws + 52*MB);
  const size_t base = 56*MB;
  unsigned* state = (unsigned*)(ws + base);
  float*    thr   = (float*)(ws + base + 4096);
  unsigned* ccnt  = (unsigned*)(ws + base + 8192);
  unsigned* ghist = (unsigned*)(ws + base + 16384);           // 1 MiB
  unsigned* cand  = (unsigned*)(ws + base + 16384 + 1048576); // 3 MiB
  const size_t off_scores = base + 16384 + 1048576 + (size_t)HH * CAPC * 4;
  float* scores = (float*)(ws + off_scores);
  const size_t perHead = (size_t)SS * SS * sizeof(float);     // 16 MiB

  int CH = 1;
  if (ws_size > off_scores + perHead)
    CH = (int)((ws_size - off_scores) / perHead);
  if (CH > HH) CH = HH;
  if (CH < 1)  CH = 1;

  split_x<<<2048, 256, 0, stream>>>(x, xh, xl);
  split_wT<<<dim3(16, 16, 4), 256, 0, stream>>>(Wq, Wk, Wv, Wo, wplanes);
  gemm_mfma_qkv<<<dim3(8, 16, 3), 256, 0, stream>>>(xh, xl, wplanes, bq, bk, bv,
                                                    Qh, Ql, Kh, Kl, V);

  for (int h0 = 0; h0 < HH; h0 += CH) {
    const int cnt = (HH - h0 < CH) ? (HH - h0) : CH;
    scores_mfma<<<dim3(16, 16, cnt), 256, 0, stream>>>(Qh, Ql, Kh, Kl, scores, h0);
    init14<<<256, 256, 0, stream>>>(ghist, ccnt);
    hist14<<<dim3(64, cnt), 512, 0, stream>>>(scores, ghist);
    scan14<<<cnt, 256, 0, stream>>>(ghist, state);
    compact14<<<dim3(64, cnt), 512, 0, stream>>>(scores, state, cand, ccnt);
    final_select_list<<<cnt, 256, 0, stream>>>(cand, ccnt, state, thr);
    softmax_pv2<<<dim3(SS/4, cnt), 256, 0, stream>>>(scores, thr, V, ctxh, ctxl, h0);
  }

  gemm_mfma_o<<<dim3(8, 16), 256, 0, stream>>>(ctxh, ctxl, wplanes, bo, out);
}

// Round 11
// 720.442 us; speedup vs baseline: 2.4003x; 1.0310x over previous
//
#include <hip/hip_runtime.h>
#include <math.h>

#define SS 2048
#define DD 1024
#define HH 16
#define CAPC 49152u   // candidate slots per head (expected ~22K at 14-bit bins)
#define LCAP 2048     // per-block LDS candidate buffer (expected ~350/block)

// quantile index: floor(0.95*(S*S-1)) = floor(3984587.85)
#define K_A 3984587u
#define K_B 3984588u
#define QFRAC 0.85f
#define WSCALE 2048.0f      // W planes pre-scaled so lo-residuals stay normal fp16
#define WSCALE_INV (1.0f/2048.0f)

typedef _Float16 f16x8 __attribute__((ext_vector_type(8)));
typedef _Float16 f16x4 __attribute__((ext_vector_type(4)));
typedef float    f32x4 __attribute__((ext_vector_type(4)));

__device__ __forceinline__ unsigned sortkey(float f) {
  unsigned b = __float_as_uint(f);
  return (b & 0x80000000u) ? ~b : (b | 0x80000000u);
}
__device__ __forceinline__ float inv_sortkey(unsigned u) {
  unsigned b = (u & 0x80000000u) ? (u ^ 0x80000000u) : ~u;
  return __uint_as_float(b);
}

// ---------------- input splitting ----------------
__global__ __launch_bounds__(256) void split_x(const float* __restrict__ x,
                                               _Float16* __restrict__ xh,
                                               _Float16* __restrict__ xl)
{
  const int i = blockIdx.x * 256 + threadIdx.x;   // float4 index, 524288 total
  float4 v = ((const float4*)x)[i];
  float vv[4] = {v.x, v.y, v.z, v.w};
  f16x4 h, l;
#pragma unroll
  for (int j = 0; j < 4; ++j) {
    _Float16 hh = (_Float16)vv[j];
    h[j] = hh;
    l[j] = (_Float16)(vv[j] - (float)hh);
  }
  ((f16x4*)xh)[i] = h;
  ((f16x4*)xl)[i] = l;
}

// W -> transposed hi/lo fp16 planes WT[n][k], scaled by 2048 (keeps lo normal).
__global__ __launch_bounds__(256) void split_wT(const float* __restrict__ Wq,
                                                const float* __restrict__ Wk,
                                                const float* __restrict__ Wv,
                                                const float* __restrict__ Wo,
                                                _Float16* __restrict__ wplanes)
{
  const int z = blockIdx.z;
  const float* W = (z == 0) ? Wq : (z == 1) ? Wk : (z == 2) ? Wv : Wo;
  _Float16* WhT = wplanes + (size_t)(2*z)     * (1024*1024);
  _Float16* WlT = wplanes + (size_t)(2*z + 1) * (1024*1024);
  __shared__ float tile[64][65];
  const int t  = threadIdx.x;
  const int r  = t >> 2;         // 0..63
  const int c0 = (t & 3) * 16;   // 0/16/32/48
  const int k0 = blockIdx.y * 64;
  const int n0 = blockIdx.x * 64;
#pragma unroll
  for (int j = 0; j < 4; ++j) {
    float4 v = *(const float4*)&W[(size_t)(k0 + r) * 1024 + n0 + c0 + j*4];
    tile[r][c0+j*4+0] = v.x; tile[r][c0+j*4+1] = v.y;
    tile[r][c0+j*4+2] = v.z; tile[r][c0+j*4+3] = v.w;
  }
  __syncthreads();
  f16x8 h0, h1, l0, l1;
#pragma unroll
  for (int j = 0; j < 8; ++j) {
    float v = tile[c0 + j][r] * WSCALE;
    _Float16 h = (_Float16)v;
    h0[j] = h; l0[j] = (_Float16)(v - (float)h);
  }
#pragma unroll
  for (int j = 0; j < 8; ++j) {
    float v = tile[c0 + 8 + j][r] * WSCALE;
    _Float16 h = (_Float16)v;
    h1[j] = h; l1[j] = (_Float16)(v - (float)h);
  }
  const size_t o = (size_t)(n0 + r) * 1024 + k0 + c0;
  *(f16x8*)&WhT[o]     = h0;
  *(f16x8*)&WhT[o + 8] = h1;
  *(f16x8*)&WlT[o]     = l0;
  *(f16x8*)&WlT[o + 8] = l1;
}

// ---------------- MFMA GEMM: O[2048,1024] = A@B + bias ----------------
// Wave tile 64x32 (acc[4][2]), block 128x64, grid (N/64, M/128[, z]) -> 3072
// waves = 12/CU (round-10's 64x64 waves gave 6/CU, MfmaUtil 15%, latency-bound).
// Same ascending-term MFMA chain per output element -> bitwise-identical.
__device__ __forceinline__ void gemm_mfma_body(const _Float16* __restrict__ Ah,
                                               const _Float16* __restrict__ Al,
                                               const _Float16* __restrict__ BhT,
                                               const _Float16* __restrict__ BlT,
                                               const float* __restrict__ bias,
                                               _Float16* __restrict__ Oh,
                                               _Float16* __restrict__ Ol,
                                               float* __restrict__ Of,
                                               int fp32out, int bm, int bn)
{
  const int wave = threadIdx.x >> 6, lane = threadIdx.x & 63;
  const int wr = wave >> 1, wc = wave & 1;
  const int m0 = bm * 128 + wr * 64;
  const int n0 = bn * 64  + wc * 32;
  const int lr = lane & 15;
  const int ko = lane >> 4;

  f32x4 acc[4][2];
#pragma unroll
  for (int i = 0; i < 4; ++i)
#pragma unroll
    for (int j = 0; j < 2; ++j) acc[i][j] = (f32x4){0.f, 0.f, 0.f, 0.f};

  for (int kk = 0; kk < 32; ++kk) {
    const int kof = kk*32 + ko*8;
    f16x8 aH[4], aL[4], bH[2], bL[2];
#pragma unroll
    for (int i = 0; i < 4; ++i) {
      const size_t aoff = (size_t)(m0 + i*16 + lr) * 1024 + kof;
      aH[i] = *(const f16x8*)(Ah + aoff);
      aL[i] = *(const f16x8*)(Al + aoff);
    }
#pragma unroll
    for (int j = 0; j < 2; ++j) {
      const size_t boff = (size_t)(n0 + j*16 + lr) * 1024 + kof;
      bH[j] = *(const f16x8*)(BhT + boff);
      bL[j] = *(const f16x8*)(BlT + boff);
    }
#pragma unroll
    for (int i = 0; i < 4; ++i)
#pragma unroll
      for (int j = 0; j < 2; ++j) {
        acc[i][j] = __builtin_amdgcn_mfma_f32_16x16x32_f16(aL[i], bL[j], acc[i][j], 0, 0, 0);
        acc[i][j] = __builtin_amdgcn_mfma_f32_16x16x32_f16(aH[i], bL[j], acc[i][j], 0, 0, 0);
        acc[i][j] = __builtin_amdgcn_mfma_f32_16x16x32_f16(aL[i], bH[j], acc[i][j], 0, 0, 0);
        acc[i][j] = __builtin_amdgcn_mfma_f32_16x16x32_f16(aH[i], bH[j], acc[i][j], 0, 0, 0);
      }
  }

#pragma unroll
  for (int i = 0; i < 4; ++i) {
#pragma unroll
    for (int j = 0; j < 2; ++j) {
#pragma unroll
      for (int r = 0; r < 4; ++r) {
        const int row = m0 + i*16 + ko*4 + r;
        const int col = n0 + j*16 + lr;
        const float val = acc[i][j][r] * WSCALE_INV + bias[col];
        if (fp32out) {
          Of[(size_t)row * 1024 + col] = val;
        } else {
          _Float16 h = (_Float16)val;
          Oh[(size_t)row * 1024 + col] = h;
          Ol[(size_t)row * 1024 + col] = (_Float16)(val - (float)h);
        }
      }
    }
  }
}

__global__ __launch_bounds__(256) void gemm_mfma_qkv(const _Float16* __restrict__ xh,
                                                     const _Float16* __restrict__ xl,
                                                     const _Float16* __restrict__ wplanes,
                                                     const float* __restrict__ bq,
                                                     const float* __restrict__ bk,
                                                     const float* __restrict__ bv,
                                                     _Float16* __restrict__ Qh,
                                                     _Float16* __restrict__ Ql,
                                                     _Float16* __restrict__ Kh,
                                                     _Float16* __restrict__ Kl,
                                                     float* __restrict__ V)
{
  const int z = blockIdx.z;
  const _Float16* BhT = wplanes + (size_t)(2*z)     * (1024*1024);
  const _Float16* BlT = wplanes + (size_t)(2*z + 1) * (1024*1024);
  const float* bias = (z == 0) ? bq : (z == 1) ? bk : bv;
  _Float16* Oh = (z == 0) ? Qh : Kh;
  _Float16* Ol = (z == 0) ? Ql : Kl;
  gemm_mfma_body(xh, xl, BhT, BlT, bias, Oh, Ol, V, (z == 2) ? 1 : 0,
                 blockIdx.y, blockIdx.x);
}

__global__ __launch_bounds__(256) void gemm_mfma_o(const _Float16* __restrict__ ctxh,
                                                   const _Float16* __restrict__ ctxl,
                                                   const _Float16* __restrict__ wplanes,
                                                   const float* __restrict__ bo,
                                                   float* __restrict__ out)
{
  gemm_mfma_body(ctxh, ctxl,
                 wplanes + (size_t)6 * (1024*1024),
                 wplanes + (size_t)7 * (1024*1024),
                 bo, nullptr, nullptr, out, 1, blockIdx.y, blockIdx.x);
}

// ---------------- scores via 4-term split-fp16 MFMA + fused 14-bit histogram ----------------
// 512 threads = 8 waves (4m x 2n of 64x64), block tile 256x128, grid (16, 8, cnt).
// Histograms the EXACT stored score values into a 64KB LDS table, flushed to
// ghist with hist14's proven if(c)-guarded atomic pattern. init14 must run first.
__global__ __launch_bounds__(512) void scores_mfma(const _Float16* __restrict__ Qh,
                                                   const _Float16* __restrict__ Ql,
                                                   const _Float16* __restrict__ Kh,
                                                   const _Float16* __restrict__ Kl,
                                                   float* __restrict__ scores,
                                                   unsigned* __restrict__ ghist,
                                                   int h0)
{
  const int bn = blockIdx.x, bm = blockIdx.y, hh = blockIdx.z;
  const int h = h0 + hh;
  const int wave = threadIdx.x >> 6, lane = threadIdx.x & 63;
  const int wr = wave >> 1, wc = wave & 1;
  const int m0 = bm * 256 + wr * 64;
  const int n0 = bn * 128 + wc * 64;
  const int lr = lane & 15;
  const int ko = lane >> 4;

  __shared__ unsigned lh[16384];   // 64 KB
  for (int i = threadIdx.x; i < 16384; i += 512) lh[i] = 0;
  __syncthreads();

  f32x4 acc[4][4];
#pragma unroll
  for (int i = 0; i < 4; ++i)
#pragma unroll
    for (int j = 0; j < 4; ++j) acc[i][j] = (f32x4){0.f, 0.f, 0.f, 0.f};

#pragma unroll
  for (int kk = 0; kk < 2; ++kk) {
    f16x8 aH[4], aL[4], bH[4], bL[4];
#pragma unroll
    for (int i = 0; i < 4; ++i) {
      const size_t aoff = (size_t)(m0 + i*16 + lr) * 1024 + h*64 + kk*32 + ko*8;
      aH[i] = *(const f16x8*)(Qh + aoff);
      aL[i] = *(const f16x8*)(Ql + aoff);
      const size_t boff = (size_t)(n0 + i*16 + lr) * 1024 + h*64 + kk*32 + ko*8;
      bH[i] = *(const f16x8*)(Kh + boff);
      bL[i] = *(const f16x8*)(Kl + boff);
    }
#pragma unroll
    for (int i = 0; i < 4; ++i)
#pragma unroll
      for (int j = 0; j < 4; ++j) {
        acc[i][j] = __builtin_amdgcn_mfma_f32_16x16x32_f16(aL[i], bL[j], acc[i][j], 0, 0, 0);
        acc[i][j] = __builtin_amdgcn_mfma_f32_16x16x32_f16(aH[i], bL[j], acc[i][j], 0, 0, 0);
        acc[i][j] = __builtin_amdgcn_mfma_f32_16x16x32_f16(aL[i], bH[j], acc[i][j], 0, 0, 0);
        acc[i][j] = __builtin_amdgcn_mfma_f32_16x16x32_f16(aH[i], bH[j], acc[i][j], 0, 0, 0);
      }
  }

#pragma unroll
  for (int i = 0; i < 4; ++i) {
#pragma unroll
    for (int j = 0; j < 4; ++j) {
#pragma unroll
      for (int r = 0; r < 4; ++r) {
        const int row = m0 + i*16 + ko*4 + r;
        const int col = n0 + j*16 + lr;
        const float val = acc[i][j][r] * 0.125f;
        scores[((size_t)hh * SS + row) * SS + col] = val;
        atomicAdd(&lh[sortkey(val) >> 18], 1u);
      }
    }
  }
  __syncthreads();
  unsigned* __restrict__ gh = ghist + (size_t)hh * 16384;
  for (int i = threadIdx.x; i < 16384; i += 512) {
    const unsigned c = lh[i];
    if (c) atomicAdd(&gh[i], c);
  }
}

// ---------------- radix select, 14-bit first digit ----------------
__global__ __launch_bounds__(256) void init14(unsigned* __restrict__ ghist,
                                              unsigned* __restrict__ ccnt)
{
  int i = blockIdx.x * 256 + threadIdx.x;
  for (; i < HH * 16384; i += gridDim.x * 256) ghist[i] = 0;
  if (blockIdx.x == 0 && threadIdx.x < HH) ccnt[threadIdx.x] = 0;
}

__global__ __launch_bounds__(256) void scan14(const unsigned* __restrict__ ghist,
                                              unsigned* __restrict__ state)
{
  const int hh = blockIdx.x;
  const int t = threadIdx.x;
  __shared__ unsigned part[256];
  __shared__ unsigned out[4];
  const unsigned* __restrict__ hb = ghist + (size_t)hh * 16384;
  unsigned s = 0;
  for (int j = 0; j < 64; ++j) s += hb[t*64 + j];
  part[t] = s;
  __syncthreads();
  if (t == 0) {
    unsigned run = 0;
    for (int i = 0; i < 256; ++i) { unsigned tmp = part[i]; part[i] = run; run += tmp; }
  }
  __syncthreads();
  const unsigned cum0 = part[t];
  if (K_A >= cum0 && K_A < cum0 + s) {
    unsigned c2 = cum0;
    for (int j = 0; j < 64; ++j) {
      const unsigned c = hb[t*64 + j];
      if (K_A < c2 + c) {
        const unsigned binA = t*64 + j;
        const unsigned residA = K_A - c2;
        unsigned binB, residB;
        if (residA + 1 < c) { binB = binA; residB = residA + 1; }
        else {
          unsigned bb = binA + 1;
          while (bb < 16384 && hb[bb] == 0) ++bb;
          if (bb >= 16384) bb = 16383;  // defensive
          binB = bb; residB = 0;
        }
        out[0] = binA; out[1] = residA; out[2] = binB; out[3] = residB;
        break;
      }
      c2 += c;
    }
  }
  __syncthreads();
  if (t < 4) state[hh*4 + t] = out[t];
}

__global__ __launch_bounds__(512) void compact14(const float* __restrict__ scores,
                                                 const unsigned* __restrict__ state,
                                                 unsigned* __restrict__ cand,
                                                 unsigned* __restrict__ ccnt)
{
  const int hh = blockIdx.y;
  __shared__ unsigned lbuf[LCAP];
  __shared__ unsigned lcnt, gbase;
  const int t = threadIdx.x;
  if (t == 0) lcnt = 0;
  __syncthreads();
  const unsigned binA = state[hh*4+0];
  const unsigned binB = state[hh*4+2];
  unsigned* __restrict__ mycand = cand + (size_t)hh * CAPC;
  const float4* base = (const float4*)(scores + (size_t)hh * SS * SS)
                       + (size_t)blockIdx.x * 16384;
  for (int i = t; i < 16384; i += 512) {
    float4 v = base[i];
#pragma unroll
    for (int e = 0; e < 4; ++e) {
      const float f = (e == 0) ? v.x : (e == 1) ? v.y : (e == 2) ? v.z : v.w;
      const unsigned u = sortkey(f);
      const unsigned bin = u >> 18;
      if (bin == binA || bin == binB) {
        unsigned id = atomicAdd(&lcnt, 1u);
        if (id < LCAP) lbuf[id] = u;
        else { unsigned g = atomicAdd(&ccnt[hh], 1u); if (g < CAPC) mycand[g] = u; }
      }
    }
  }
  __syncthreads();
  const unsigned n = (lcnt < LCAP) ? lcnt : LCAP;
  if (t == 0) gbase = n ? atomicAdd(&ccnt[hh], n) : 0u;
  __syncthreads();
  const unsigned gb = gbase;
  for (unsigned i = t; i < n; i += 512)
    if (gb + i < CAPC) mycand[gb + i] = lbuf[i];
}

__global__ __launch_bounds__(256) void final_select_list(const unsigned* __restrict__ cand,
                                                         const unsigned* __restrict__ ccnt,
                                                         const unsigned* __restrict__ state,
                                                         float* __restrict__ thr)
{
  const int hh = blockIdx.x;
  const int t = threadIdx.x;
  __shared__ unsigned hist[256];
  __shared__ unsigned digitS, kresS;
  __shared__ float valS[2];
  unsigned n = ccnt[hh]; if (n > CAPC) n = CAPC;
  const unsigned* __restrict__ list = cand + (size_t)hh * CAPC;
  for (int tgt = 0; tgt < 2; ++tgt) {
    unsigned pfx = state[hh*4 + tgt*2];
    unsigned k   = state[hh*4 + tgt*2 + 1];
    for (int r = 0; r < 3; ++r) {
      const int s = (r == 0) ? 10 : (r == 1) ? 2 : 0;
      const int w = (r == 2) ? 2 : 8;
      const unsigned nb = 1u << w;
      hist[t] = 0;
      __syncthreads();
      for (unsigned i = t; i < n; i += 256) {
        const unsigned u = list[i];
        if ((u >> (s + w)) == pfx) atomicAdd(&hist[(u >> s) & (nb - 1)], 1u);
      }
      __syncthreads();
      if (t == 0) {
        unsigned cum = 0, b = 0;
        for (; b < nb; ++b) { const unsigned c = hist[b]; if (cum + c > k) break; cum += c; }
        if (b == nb) b = nb - 1;
        digitS = b; kresS = k - cum;
      }
      __syncthreads();
      pfx = (pfx << w) | digitS;
      k = kresS;
    }
    if (t == 0) valS[tgt] = inv_sortkey(pfx);
    __syncthreads();
  }
  if (t == 0) thr[hh] = valS[0] + QFRAC * (valS[1] - valS[0]);
}

// ---------------- wave-per-row masked softmax + ballot-compacted sparse PV ----------------
__global__ __launch_bounds__(256) void softmax_pv2(const float* __restrict__ scores,
                                                   const float* __restrict__ thrArr,
                                                   const float* __restrict__ V,
                                                   _Float16* __restrict__ ctxh,
                                                   _Float16* __restrict__ ctxl,
                                                   int h0)
{
  const int wave = threadIdx.x >> 6;
  const int lane = threadIdx.x & 63;
  const int row  = blockIdx.x * 4 + wave;
  const int hh   = blockIdx.y;
  const int h    = h0 + hh;
  const float thr = thrArr[hh];
  const float* __restrict__ srow = scores + ((size_t)hh * SS + row) * SS;

  float p[32];
#pragma unroll
  for (int t = 0; t < 32; ++t) p[t] = srow[t*64 + lane];

  float m = -INFINITY;
#pragma unroll
  for (int t = 0; t < 32; ++t)
    if (p[t] >= thr) m = fmaxf(m, p[t]);
#pragma unroll
  for (int off = 32; off; off >>= 1) m = fmaxf(m, __shfl_xor(m, off));

  float sum = 0.f;
#pragma unroll
  for (int t = 0; t < 32; ++t) {
    float e = (p[t] >= thr) ? __expf(p[t] - m) : 0.f;
    p[t] = e;
    sum += e;
  }
#pragma unroll
  for (int off = 32; off; off >>= 1) sum += __shfl_xor(sum, off);

  float acc0 = 0.f, acc1 = 0.f;
  const float* __restrict__ vcol = V + h*64 + lane;
#pragma unroll
  for (int t = 0; t < 32; ++t) {
    unsigned long long mk = __ballot(p[t] != 0.f);
    const float* __restrict__ vt = vcol + (size_t)t * 64 * 1024;
    while (mk) {
      int b0 = __ffsll(mk) - 1; mk &= mk - 1;
      if (mk) {
        int b1 = __ffsll(mk) - 1; mk &= mk - 1;
        float va = vt[(size_t)b0 * 1024];
        float vb = vt[(size_t)b1 * 1024];
        acc0 = fmaf(__shfl(p[t], b0), va, acc0);
        acc1 = fmaf(__shfl(p[t], b1), vb, acc1);
      } else {
        acc0 = fmaf(__shfl(p[t], b0), vt[(size_t)b0 * 1024], acc0);
      }
    }
  }
  const float val = (acc0 + acc1) / sum;
  const size_t oidx = (size_t)row * 1024 + h*64 + lane;
  _Float16 hv = (_Float16)val;
  ctxh[oidx] = hv;
  ctxl[oidx] = (_Float16)(val - (float)hv);
}

// ---------------- host ----------------
extern "C" void kernel_launch(void* const* d_in, const int* in_sizes, int n_in,
                              void* d_out, int out_size, void* d_ws, size_t ws_size,
                              hipStream_t stream)
{
  const float* x  = (const float*)d_in[0];
  const float* Wq = (const float*)d_in[1];
  const float* bq = (const float*)d_in[2];
  const float* Wk = (const float*)d_in[3];
  const float* bk = (const float*)d_in[4];
  const float* Wv = (const float*)d_in[5];
  const float* bv = (const float*)d_in[6];
  const float* Wo = (const float*)d_in[7];
  const float* bo = (const float*)d_in[8];
  float* out = (float*)d_out;
  char*  ws  = (char*)d_ws;

  const size_t MB = 1u << 20;
  _Float16* xh      = (_Float16*)(ws + 0*MB);    // 4 MiB each fp16 plane
  _Float16* xl      = (_Float16*)(ws + 4*MB);
  _Float16* wplanes = (_Float16*)(ws + 8*MB);    // 8 x 2 MiB transposed W planes
  _Float16* Qh      = (_Float16*)(ws + 24*MB);
  _Float16* Ql      = (_Float16*)(ws + 28*MB);
  _Float16* Kh      = (_Float16*)(ws + 32*MB);
  _Float16* Kl      = (_Float16*)(ws + 36*MB);
  float*    V       = (float*)   (ws + 40*MB);   // 8 MiB fp32
  _Float16* ctxh    = (_Float16*)(ws + 48*MB);
  _Float16* ctxl    = (_Float16*)(ws + 52*MB);
  const size_t base = 56*MB;
  unsigned* state = (unsigned*)(ws + base);
  float*    thr   = (float*)(ws + base + 4096);
  unsigned* ccnt  = (unsigned*)(ws + base + 8192);
  unsigned* ghist = (unsigned*)(ws + base + 16384);           // 1 MiB
  unsigned* cand  = (unsigned*)(ws + base + 16384 + 1048576); // 3 MiB
  const size_t off_scores = base + 16384 + 1048576 + (size_t)HH * CAPC * 4;
  float* scores = (float*)(ws + off_scores);
  const size_t perHead = (size_t)SS * SS * sizeof(float);     // 16 MiB

  int CH = 1;
  if (ws_size > off_scores + perHead)
    CH = (int)((ws_size - off_scores) / perHead);
  if (CH > HH) CH = HH;
  if (CH < 1)  CH = 1;

  split_x<<<2048, 256, 0, stream>>>(x, xh, xl);
  split_wT<<<dim3(16, 16, 4), 256, 0, stream>>>(Wq, Wk, Wv, Wo, wplanes);
  gemm_mfma_qkv<<<dim3(16, 16, 3), 256, 0, stream>>>(xh, xl, wplanes, bq, bk, bv,
                                                     Qh, Ql, Kh, Kl, V);

  for (int h0 = 0; h0 < HH; h0 += CH) {
    const int cnt = (HH - h0 < CH) ? (HH - h0) : CH;
    init14<<<256, 256, 0, stream>>>(ghist, ccnt);
    scores_mfma<<<dim3(16, 8, cnt), 512, 0, stream>>>(Qh, Ql, Kh, Kl, scores, ghist, h0);
    scan14<<<cnt, 256, 0, stream>>>(ghist, state);
    compact14<<<dim3(64, cnt), 512, 0, stream>>>(scores, state, cand, ccnt);
    final_select_list<<<cnt, 256, 0, stream>>>(cand, ccnt, state, thr);
    softmax_pv2<<<dim3(SS/4, cnt), 256, 0, stream>>>(scores, thr, V, ctxh, ctxl, h0);
  }

  gemm_mfma_o<<<dim3(16, 16), 256, 0, stream>>>(ctxh, ctxl, wplanes, bo, out);
}

// Round 12
// 601.137 us; speedup vs baseline: 2.8767x; 1.1985x over previous
//
#include <hip/hip_runtime.h>
#include <math.h>

#define SS 2048
#define DD 1024
#define HH 16
#define CAPC 49152u   // candidate slots per head (expected ~22K at 14-bit bins)
#define LCAP 2048     // per-block LDS candidate buffer (expected ~90/block)

// quantile index: floor(0.95*(S*S-1)) = floor(3984587.85)
#define K_A 3984587u
#define K_B 3984588u
#define QFRAC 0.85f
#define WSCALE 2048.0f      // W planes pre-scaled so lo-residuals stay normal fp16
#define WSCALE_INV (1.0f/2048.0f)
#define ESHIFT 4.0f         // exp(s - thr - ESHIFT): kept P in [e^-4, ~e^6] — fp16-safe

typedef _Float16 f16x8 __attribute__((ext_vector_type(8)));
typedef _Float16 f16x4 __attribute__((ext_vector_type(4)));
typedef float    f32x4 __attribute__((ext_vector_type(4)));

__device__ __forceinline__ unsigned sortkey(float f) {
  unsigned b = __float_as_uint(f);
  return (b & 0x80000000u) ? ~b : (b | 0x80000000u);
}
__device__ __forceinline__ float inv_sortkey(unsigned u) {
  unsigned b = (u & 0x80000000u) ? (u ^ 0x80000000u) : ~u;
  return __uint_as_float(b);
}

// ---------------- input splitting ----------------
__global__ __launch_bounds__(256) void split_x(const float* __restrict__ x,
                                               _Float16* __restrict__ xh,
                                               _Float16* __restrict__ xl)
{
  const int i = blockIdx.x * 256 + threadIdx.x;   // float4 index, 524288 total
  float4 v = ((const float4*)x)[i];
  float vv[4] = {v.x, v.y, v.z, v.w};
  f16x4 h, l;
#pragma unroll
  for (int j = 0; j < 4; ++j) {
    _Float16 hh = (_Float16)vv[j];
    h[j] = hh;
    l[j] = (_Float16)(vv[j] - (float)hh);
  }
  ((f16x4*)xh)[i] = h;
  ((f16x4*)xl)[i] = l;
}

// W -> transposed hi/lo fp16 planes WT[n][k], scaled by 2048 (keeps lo normal).
__global__ __launch_bounds__(256) void split_wT(const float* __restrict__ Wq,
                                                const float* __restrict__ Wk,
                                                const float* __restrict__ Wv,
                                                const float* __restrict__ Wo,
                                                _Float16* __restrict__ wplanes)
{
  const int z = blockIdx.z;
  const float* W = (z == 0) ? Wq : (z == 1) ? Wk : (z == 2) ? Wv : Wo;
  _Float16* WhT = wplanes + (size_t)(2*z)     * (1024*1024);
  _Float16* WlT = wplanes + (size_t)(2*z + 1) * (1024*1024);
  __shared__ float tile[64][65];
  const int t  = threadIdx.x;
  const int r  = t >> 2;         // 0..63
  const int c0 = (t & 3) * 16;   // 0/16/32/48
  const int k0 = blockIdx.y * 64;
  const int n0 = blockIdx.x * 64;
#pragma unroll
  for (int j = 0; j < 4; ++j) {
    float4 v = *(const float4*)&W[(size_t)(k0 + r) * 1024 + n0 + c0 + j*4];
    tile[r][c0+j*4+0] = v.x; tile[r][c0+j*4+1] = v.y;
    tile[r][c0+j*4+2] = v.z; tile[r][c0+j*4+3] = v.w;
  }
  __syncthreads();
  f16x8 h0, h1, l0, l1;
#pragma unroll
  for (int j = 0; j < 8; ++j) {
    float v = tile[c0 + j][r] * WSCALE;
    _Float16 h = (_Float16)v;
    h0[j] = h; l0[j] = (_Float16)(v - (float)h);
  }
#pragma unroll
  for (int j = 0; j < 8; ++j) {
    float v = tile[c0 + 8 + j][r] * WSCALE;
    _Float16 h = (_Float16)v;
    h1[j] = h; l1[j] = (_Float16)(v - (float)h);
  }
  const size_t o = (size_t)(n0 + r) * 1024 + k0 + c0;
  *(f16x8*)&WhT[o]     = h0;
  *(f16x8*)&WhT[o + 8] = h1;
  *(f16x8*)&WlT[o]     = l0;
  *(f16x8*)&WlT[o + 8] = l1;
}

// ---------------- MFMA GEMM (round-10 proven 64x64 wave tile) ----------------
// mode 0: fp16 hi/lo planes row-major (Q,K). mode 1: fp32 (final out).
// mode 2: fp16 hi/lo planes TRANSPOSED Vt[d_global][row] (feeds flash PV B-operand).
__device__ __forceinline__ void gemm_mfma_body(const _Float16* __restrict__ Ah,
                                               const _Float16* __restrict__ Al,
                                               const _Float16* __restrict__ BhT,
                                               const _Float16* __restrict__ BlT,
                                               const float* __restrict__ bias,
                                               _Float16* __restrict__ Oh,
                                               _Float16* __restrict__ Ol,
                                               float* __restrict__ Of,
                                               int mode, int bm, int bn)
{
  const int wave = threadIdx.x >> 6, lane = threadIdx.x & 63;
  const int wr = wave >> 1, wc = wave & 1;
  const int m0 = bm * 128 + wr * 64;
  const int n0 = bn * 128 + wc * 64;
  const int lr = lane & 15;
  const int ko = lane >> 4;

  f32x4 acc[4][4];
#pragma unroll
  for (int i = 0; i < 4; ++i)
#pragma unroll
    for (int j = 0; j < 4; ++j) acc[i][j] = (f32x4){0.f, 0.f, 0.f, 0.f};

  for (int kk = 0; kk < 32; ++kk) {
    const int kof = kk*32 + ko*8;
    f16x8 aH[4], aL[4], bH[4], bL[4];
#pragma unroll
    for (int i = 0; i < 4; ++i) {
      const size_t aoff = (size_t)(m0 + i*16 + lr) * 1024 + kof;
      aH[i] = *(const f16x8*)(Ah + aoff);
      aL[i] = *(const f16x8*)(Al + aoff);
      const size_t boff = (size_t)(n0 + i*16 + lr) * 1024 + kof;
      bH[i] = *(const f16x8*)(BhT + boff);
      bL[i] = *(const f16x8*)(BlT + boff);
    }
#pragma unroll
    for (int i = 0; i < 4; ++i)
#pragma unroll
      for (int j = 0; j < 4; ++j) {
        acc[i][j] = __builtin_amdgcn_mfma_f32_16x16x32_f16(aL[i], bL[j], acc[i][j], 0, 0, 0);
        acc[i][j] = __builtin_amdgcn_mfma_f32_16x16x32_f16(aH[i], bL[j], acc[i][j], 0, 0, 0);
        acc[i][j] = __builtin_amdgcn_mfma_f32_16x16x32_f16(aL[i], bH[j], acc[i][j], 0, 0, 0);
        acc[i][j] = __builtin_amdgcn_mfma_f32_16x16x32_f16(aH[i], bH[j], acc[i][j], 0, 0, 0);
      }
  }

#pragma unroll
  for (int i = 0; i < 4; ++i) {
#pragma unroll
    for (int j = 0; j < 4; ++j) {
      if (mode == 2) {
        // transposed store: Vt[col][row0..row0+3] hi/lo
        const int col  = n0 + j*16 + lr;
        const int row0 = m0 + i*16 + ko*4;
        f16x4 hv, lv;
#pragma unroll
        for (int r = 0; r < 4; ++r) {
          const float val = acc[i][j][r] * WSCALE_INV + bias[col];
          _Float16 h = (_Float16)val;
          hv[r] = h; lv[r] = (_Float16)(val - (float)h);
        }
        *(f16x4*)&Oh[(size_t)col * 2048 + row0] = hv;
        *(f16x4*)&Ol[(size_t)col * 2048 + row0] = lv;
      } else {
#pragma unroll
        for (int r = 0; r < 4; ++r) {
          const int row = m0 + i*16 + ko*4 + r;
          const int col = n0 + j*16 + lr;
          const float val = acc[i][j][r] * WSCALE_INV + bias[col];
          if (mode == 1) {
            Of[(size_t)row * 1024 + col] = val;
          } else {
            _Float16 h = (_Float16)val;
            Oh[(size_t)row * 1024 + col] = h;
            Ol[(size_t)row * 1024 + col] = (_Float16)(val - (float)h);
          }
        }
      }
    }
  }
}

__global__ __launch_bounds__(256) void gemm_mfma_qkv(const _Float16* __restrict__ xh,
                                                     const _Float16* __restrict__ xl,
                                                     const _Float16* __restrict__ wplanes,
                                                     const float* __restrict__ bq,
                                                     const float* __restrict__ bk,
                                                     const float* __restrict__ bv,
                                                     _Float16* __restrict__ Qh,
                                                     _Float16* __restrict__ Ql,
                                                     _Float16* __restrict__ Kh,
                                                     _Float16* __restrict__ Kl,
                                                     _Float16* __restrict__ VtH,
                                                     _Float16* __restrict__ VtL)
{
  const int z = blockIdx.z;
  const _Float16* BhT = wplanes + (size_t)(2*z)     * (1024*1024);
  const _Float16* BlT = wplanes + (size_t)(2*z + 1) * (1024*1024);
  const float* bias = (z == 0) ? bq : (z == 1) ? bk : bv;
  _Float16* Oh = (z == 0) ? Qh : (z == 1) ? Kh : VtH;
  _Float16* Ol = (z == 0) ? Ql : (z == 1) ? Kl : VtL;
  gemm_mfma_body(xh, xl, BhT, BlT, bias, Oh, Ol, nullptr, (z == 2) ? 2 : 0,
                 blockIdx.y, blockIdx.x);
}

__global__ __launch_bounds__(256) void gemm_mfma_o(const _Float16* __restrict__ ctxh,
                                                   const _Float16* __restrict__ ctxl,
                                                   const _Float16* __restrict__ wplanes,
                                                   const float* __restrict__ bo,
                                                   float* __restrict__ out)
{
  gemm_mfma_body(ctxh, ctxl,
                 wplanes + (size_t)6 * (1024*1024),
                 wplanes + (size_t)7 * (1024*1024),
                 bo, nullptr, nullptr, out, 1, blockIdx.y, blockIdx.x);
}

// ---------------- pass 1: scores (recomputable MFMA chain) + fused 14-bit hist, NO store ----------------
// 512 threads = 8 waves (4m x 2n of 64x64), block tile 256x128, grid (16, 8, 16).
// The per-(row,col) MFMA chain (kk loop x LL,HL,LH,HH) is IDENTICAL in
// compact_recompute and flash_pv -> bitwise-identical scores across kernels.
__global__ __launch_bounds__(512) void scores_hist(const _Float16* __restrict__ Qh,
                                                   const _Float16* __restrict__ Ql,
                                                   const _Float16* __restrict__ Kh,
                                                   const _Float16* __restrict__ Kl,
                                                   unsigned* __restrict__ ghist)
{
  const int bn = blockIdx.x, bm = blockIdx.y, h = blockIdx.z;
  const int wave = threadIdx.x >> 6, lane = threadIdx.x & 63;
  const int wr = wave >> 1, wc = wave & 1;
  const int m0 = bm * 256 + wr * 64;
  const int n0 = bn * 128 + wc * 64;
  const int lr = lane & 15;
  const int ko = lane >> 4;

  __shared__ unsigned lh[16384];   // 64 KB
  for (int i = threadIdx.x; i < 16384; i += 512) lh[i] = 0;
  __syncthreads();

  f32x4 acc[4][4];
#pragma unroll
  for (int i = 0; i < 4; ++i)
#pragma unroll
    for (int j = 0; j < 4; ++j) acc[i][j] = (f32x4){0.f, 0.f, 0.f, 0.f};

#pragma unroll
  for (int kk = 0; kk < 2; ++kk) {
    f16x8 aH[4], aL[4], bH[4], bL[4];
#pragma unroll
    for (int i = 0; i < 4; ++i) {
      const size_t aoff = (size_t)(m0 + i*16 + lr) * 1024 + h*64 + kk*32 + ko*8;
      aH[i] = *(const f16x8*)(Qh + aoff);
      aL[i] = *(const f16x8*)(Ql + aoff);
      const size_t boff = (size_t)(n0 + i*16 + lr) * 1024 + h*64 + kk*32 + ko*8;
      bH[i] = *(const f16x8*)(Kh + boff);
      bL[i] = *(const f16x8*)(Kl + boff);
    }
#pragma unroll
    for (int i = 0; i < 4; ++i)
#pragma unroll
      for (int j = 0; j < 4; ++j) {
        acc[i][j] = __builtin_amdgcn_mfma_f32_16x16x32_f16(aL[i], bL[j], acc[i][j], 0, 0, 0);
        acc[i][j] = __builtin_amdgcn_mfma_f32_16x16x32_f16(aH[i], bL[j], acc[i][j], 0, 0, 0);
        acc[i][j] = __builtin_amdgcn_mfma_f32_16x16x32_f16(aL[i], bH[j], acc[i][j], 0, 0, 0);
        acc[i][j] = __builtin_amdgcn_mfma_f32_16x16x32_f16(aH[i], bH[j], acc[i][j], 0, 0, 0);
      }
  }

#pragma unroll
  for (int i = 0; i < 4; ++i)
#pragma unroll
    for (int j = 0; j < 4; ++j)
#pragma unroll
      for (int r = 0; r < 4; ++r) {
        const float val = acc[i][j][r] * 0.125f;
        atomicAdd(&lh[sortkey(val) >> 18], 1u);
      }
  __syncthreads();
  unsigned* __restrict__ gh = ghist + (size_t)h * 16384;
  for (int i = threadIdx.x; i < 16384; i += 512) {
    const unsigned c = lh[i];
    if (c) atomicAdd(&gh[i], c);
  }
}

// ---------------- radix select ----------------
__global__ __launch_bounds__(256) void init14(unsigned* __restrict__ ghist,
                                              unsigned* __restrict__ ccnt)
{
  int i = blockIdx.x * 256 + threadIdx.x;
  for (; i < HH * 16384; i += gridDim.x * 256) ghist[i] = 0;
  if (blockIdx.x == 0 && threadIdx.x < HH) ccnt[threadIdx.x] = 0;
}

__global__ __launch_bounds__(256) void scan14(const unsigned* __restrict__ ghist,
                                              unsigned* __restrict__ state)
{
  const int hh = blockIdx.x;
  const int t = threadIdx.x;
  __shared__ unsigned part[256];
  __shared__ unsigned out[4];
  const unsigned* __restrict__ hb = ghist + (size_t)hh * 16384;
  unsigned s = 0;
  for (int j = 0; j < 64; ++j) s += hb[t*64 + j];
  part[t] = s;
  __syncthreads();
  if (t == 0) {
    unsigned run = 0;
    for (int i = 0; i < 256; ++i) { unsigned tmp = part[i]; part[i] = run; run += tmp; }
  }
  __syncthreads();
  const unsigned cum0 = part[t];
  if (K_A >= cum0 && K_A < cum0 + s) {
    unsigned c2 = cum0;
    for (int j = 0; j < 64; ++j) {
      const unsigned c = hb[t*64 + j];
      if (K_A < c2 + c) {
        const unsigned binA = t*64 + j;
        const unsigned residA = K_A - c2;
        unsigned binB, residB;
        if (residA + 1 < c) { binB = binA; residB = residA + 1; }
        else {
          unsigned bb = binA + 1;
          while (bb < 16384 && hb[bb] == 0) ++bb;
          if (bb >= 16384) bb = 16383;  // defensive
          binB = bb; residB = 0;
        }
        out[0] = binA; out[1] = residA; out[2] = binB; out[3] = residB;
        break;
      }
      c2 += c;
    }
  }
  __syncthreads();
  if (t < 4) state[hh*4 + t] = out[t];
}

// ---------------- pass 2: recompute scores, compact candidates in bins A/B ----------------
// Identical MFMA chain as scores_hist (bitwise-same values); two-phase LDS
// reservation (round-5 validated; one global atomic per block).
__global__ __launch_bounds__(512) void compact_recompute(const _Float16* __restrict__ Qh,
                                                         const _Float16* __restrict__ Ql,
                                                         const _Float16* __restrict__ Kh,
                                                         const _Float16* __restrict__ Kl,
                                                         const unsigned* __restrict__ state,
                                                         unsigned* __restrict__ cand,
                                                         unsigned* __restrict__ ccnt)
{
  const int bn = blockIdx.x, bm = blockIdx.y, h = blockIdx.z;
  const int wave = threadIdx.x >> 6, lane = threadIdx.x & 63;
  const int wr = wave >> 1, wc = wave & 1;
  const int m0 = bm * 256 + wr * 64;
  const int n0 = bn * 128 + wc * 64;
  const int lr = lane & 15;
  const int ko = lane >> 4;

  __shared__ unsigned lbuf[LCAP];
  __shared__ unsigned lcnt, gbase;
  if (threadIdx.x == 0) lcnt = 0;
  __syncthreads();
  const unsigned binA = state[h*4+0];
  const unsigned binB = state[h*4+2];
  unsigned* __restrict__ mycand = cand + (size_t)h * CAPC;

  f32x4 acc[4][4];
#pragma unroll
  for (int i = 0; i < 4; ++i)
#pragma unroll
    for (int j = 0; j < 4; ++j) acc[i][j] = (f32x4){0.f, 0.f, 0.f, 0.f};

#pragma unroll
  for (int kk = 0; kk < 2; ++kk) {
    f16x8 aH[4], aL[4], bH[4], bL[4];
#pragma unroll
    for (int i = 0; i < 4; ++i) {
      const size_t aoff = (size_t)(m0 + i*16 + lr) * 1024 + h*64 + kk*32 + ko*8;
      aH[i] = *(const f16x8*)(Qh + aoff);
      aL[i] = *(const f16x8*)(Ql + aoff);
      const size_t boff = (size_t)(n0 + i*16 + lr) * 1024 + h*64 + kk*32 + ko*8;
      bH[i] = *(const f16x8*)(Kh + boff);
      bL[i] = *(const f16x8*)(Kl + boff);
    }
#pragma unroll
    for (int i = 0; i < 4; ++i)
#pragma unroll
      for (int j = 0; j < 4; ++j) {
        acc[i][j] = __builtin_amdgcn_mfma_f32_16x16x32_f16(aL[i], bL[j], acc[i][j], 0, 0, 0);
        acc[i][j] = __builtin_amdgcn_mfma_f32_16x16x32_f16(aH[i], bL[j], acc[i][j], 0, 0, 0);
        acc[i][j] = __builtin_amdgcn_mfma_f32_16x16x32_f16(aL[i], bH[j], acc[i][j], 0, 0, 0);
        acc[i][j] = __builtin_amdgcn_mfma_f32_16x16x32_f16(aH[i], bH[j], acc[i][j], 0, 0, 0);
      }
  }

#pragma unroll
  for (int i = 0; i < 4; ++i)
#pragma unroll
    for (int j = 0; j < 4; ++j)
#pragma unroll
      for (int r = 0; r < 4; ++r) {
        const float val = acc[i][j][r] * 0.125f;
        const unsigned u = sortkey(val);
        const unsigned bin = u >> 18;
        if (bin == binA || bin == binB) {
          unsigned id = atomicAdd(&lcnt, 1u);
          if (id < LCAP) lbuf[id] = u;
          else { unsigned g = atomicAdd(&ccnt[h], 1u); if (g < CAPC) mycand[g] = u; }
        }
      }
  __syncthreads();
  const unsigned n = (lcnt < LCAP) ? lcnt : LCAP;
  if (threadIdx.x == 0) gbase = n ? atomicAdd(&ccnt[h], n) : 0u;
  __syncthreads();
  const unsigned gb = gbase;
  for (unsigned i = threadIdx.x; i < n; i += 512)
    if (gb + i < CAPC) mycand[gb + i] = lbuf[i];
}

__global__ __launch_bounds__(256) void final_select_list(const unsigned* __restrict__ cand,
                                                         const unsigned* __restrict__ ccnt,
                                                         const unsigned* __restrict__ state,
                                                         float* __restrict__ thr)
{
  const int hh = blockIdx.x;
  const int t = threadIdx.x;
  __shared__ unsigned hist[256];
  __shared__ unsigned digitS, kresS;
  __shared__ float valS[2];
  unsigned n = ccnt[hh]; if (n > CAPC) n = CAPC;
  const unsigned* __restrict__ list = cand + (size_t)hh * CAPC;
  for (int tgt = 0; tgt < 2; ++tgt) {
    unsigned pfx = state[hh*4 + tgt*2];
    unsigned k   = state[hh*4 + tgt*2 + 1];
    for (int r = 0; r < 3; ++r) {
      const int s = (r == 0) ? 10 : (r == 1) ? 2 : 0;
      const int w = (r == 2) ? 2 : 8;
      const unsigned nb = 1u << w;
      hist[t] = 0;
      __syncthreads();
      for (unsigned i = t; i < n; i += 256) {
        const unsigned u = list[i];
        if ((u >> (s + w)) == pfx) atomicAdd(&hist[(u >> s) & (nb - 1)], 1u);
      }
      __syncthreads();
      if (t == 0) {
        unsigned cum = 0, b = 0;
        for (; b < nb; ++b) { const unsigned c = hist[b]; if (cum + c > k) break; cum += c; }
        if (b == nb) b = nb - 1;
        digitS = b; kresS = k - cum;
      }
      __syncthreads();
      pfx = (pfx << w) | digitS;
      k = kresS;
    }
    if (t == 0) valS[tgt] = inv_sortkey(pfx);
    __syncthreads();
  }
  if (t == 0) thr[hh] = valS[0] + QFRAC * (valS[1] - valS[0]);
}

// ---------------- pass 3: flash softmax+PV (recompute S, never materialize) ----------------
// Block = 64 Q-rows x 1 head, 4 waves. Per 128-key tile: each wave computes its
// 64x32 S-quadrant (identical MFMA chain -> bitwise-same scores), masks vs thr,
// P = exp(s - thr - ESHIFT) (softmax shift-invariant; P in fp16-safe range),
// stores P to padded LDS, then all 4 waves do PV MFMA (wave owns 16 of 64 dims)
// with V from transposed fp16 hi/lo planes. Rowsum in fp32 registers.
__global__ __launch_bounds__(256) void flash_pv(const _Float16* __restrict__ Qh,
                                                const _Float16* __restrict__ Ql,
                                                const _Float16* __restrict__ Kh,
                                                const _Float16* __restrict__ Kl,
                                                const _Float16* __restrict__ VtH,
                                                const _Float16* __restrict__ VtL,
                                                const float* __restrict__ thrArr,
                                                _Float16* __restrict__ ctxh,
                                                _Float16* __restrict__ ctxl)
{
  const int bm = blockIdx.x;          // 0..31 -> rows bm*64
  const int h  = blockIdx.y;
  const int wave = threadIdx.x >> 6, lane = threadIdx.x & 63;
  const int lr = lane & 15;
  const int ko = lane >> 4;
  const int m0 = bm * 64;
  const float thr = thrArr[h];

  __shared__ _Float16 Plds[64][136];  // pad 128->136: row stride 272B = 68 dwords (4 mod 32)
  __shared__ float rsLDS[64][4];

  // Q fragments are kt-invariant: hoist
  f16x8 qH[4][2], qL[4][2];
#pragma unroll
  for (int i = 0; i < 4; ++i)
#pragma unroll
    for (int kk = 0; kk < 2; ++kk) {
      const size_t aoff = (size_t)(m0 + i*16 + lr) * 1024 + h*64 + kk*32 + ko*8;
      qH[i][kk] = *(const f16x8*)(Qh + aoff);
      qL[i][kk] = *(const f16x8*)(Ql + aoff);
    }

  f32x4 oacc[4];
#pragma unroll
  for (int i = 0; i < 4; ++i) oacc[i] = (f32x4){0.f, 0.f, 0.f, 0.f};
  float rs[4][4];
#pragma unroll
  for (int i = 0; i < 4; ++i)
#pragma unroll
    for (int r = 0; r < 4; ++r) rs[i][r] = 0.f;

  const int d0 = wave * 16;   // PV: wave owns dims d0..d0+15

  for (int kt = 0; kt < 16; ++kt) {
    const int n0 = kt*128 + wave*32;   // S: wave owns keys n0..n0+31
    f32x4 sacc[4][2];
#pragma unroll
    for (int i = 0; i < 4; ++i)
#pragma unroll
      for (int j = 0; j < 2; ++j) sacc[i][j] = (f32x4){0.f, 0.f, 0.f, 0.f};

#pragma unroll
    for (int kk = 0; kk < 2; ++kk) {
      f16x8 bH[2], bL[2];
#pragma unroll
      for (int j = 0; j < 2; ++j) {
        const size_t boff = (size_t)(n0 + j*16 + lr) * 1024 + h*64 + kk*32 + ko*8;
        bH[j] = *(const f16x8*)(Kh + boff);
        bL[j] = *(const f16x8*)(Kl + boff);
      }
#pragma unroll
      for (int i = 0; i < 4; ++i)
#pragma unroll
        for (int j = 0; j < 2; ++j) {
          sacc[i][j] = __builtin_amdgcn_mfma_f32_16x16x32_f16(qL[i][kk], bL[j], sacc[i][j], 0, 0, 0);
          sacc[i][j] = __builtin_amdgcn_mfma_f32_16x16x32_f16(qH[i][kk], bL[j], sacc[i][j], 0, 0, 0);
          sacc[i][j] = __builtin_amdgcn_mfma_f32_16x16x32_f16(qL[i][kk], bH[j], sacc[i][j], 0, 0, 0);
          sacc[i][j] = __builtin_amdgcn_mfma_f32_16x16x32_f16(qH[i][kk], bH[j], sacc[i][j], 0, 0, 0);
        }
    }

    // mask + exp + P->LDS + rowsum partials
#pragma unroll
    for (int i = 0; i < 4; ++i)
#pragma unroll
      for (int j = 0; j < 2; ++j)
#pragma unroll
        for (int r = 0; r < 4; ++r) {
          const float val = sacc[i][j][r] * 0.125f;
          const float p = (val >= thr) ? __expf(val - thr - ESHIFT) : 0.f;
          rs[i][r] += p;
          Plds[i*16 + ko*4 + r][wave*32 + j*16 + lr] = (_Float16)p;
        }
    __syncthreads();

    // PV: oacc[i] over dims d0+lr, keys kt*128..+127
#pragma unroll
    for (int kk2 = 0; kk2 < 4; ++kk2) {
      f16x8 pa[4];
#pragma unroll
      for (int i = 0; i < 4; ++i)
        pa[i] = *(const f16x8*)&Plds[i*16 + lr][kk2*32 + ko*8];
      const size_t vo = (size_t)(h*64 + d0 + lr) * 2048 + kt*128 + kk2*32 + ko*8;
      const f16x8 vH = *(const f16x8*)(VtH + vo);
      const f16x8 vL = *(const f16x8*)(VtL + vo);
#pragma unroll
      for (int i = 0; i < 4; ++i) {
        oacc[i] = __builtin_amdgcn_mfma_f32_16x16x32_f16(pa[i], vL, oacc[i], 0, 0, 0);
        oacc[i] = __builtin_amdgcn_mfma_f32_16x16x32_f16(pa[i], vH, oacc[i], 0, 0, 0);
      }
    }
    __syncthreads();   // before next kt overwrites Plds
  }

  // rowsum: reduce across the 16 lanes of each ko-group (cols), then across waves (key-quarters)
#pragma unroll
  for (int i = 0; i < 4; ++i)
#pragma unroll
    for (int r = 0; r < 4; ++r) {
      float v = rs[i][r];
      v += __shfl_xor(v, 1); v += __shfl_xor(v, 2);
      v += __shfl_xor(v, 4); v += __shfl_xor(v, 8);
      rs[i][r] = v;
    }
  if (lr == 0) {
#pragma unroll
    for (int i = 0; i < 4; ++i)
#pragma unroll
      for (int r = 0; r < 4; ++r)
        rsLDS[i*16 + ko*4 + r][wave] = rs[i][r];
  }
  __syncthreads();

  // normalize + fp16-split store of ctx
#pragma unroll
  for (int i = 0; i < 4; ++i)
#pragma unroll
    for (int r = 0; r < 4; ++r) {
      const int lrow = i*16 + ko*4 + r;
      const float tot = rsLDS[lrow][0] + rsLDS[lrow][1] + rsLDS[lrow][2] + rsLDS[lrow][3];
      const float val = oacc[i][r] / tot;
      const size_t oidx = (size_t)(m0 + lrow) * 1024 + h*64 + d0 + lr;
      _Float16 hv = (_Float16)val;
      ctxh[oidx] = hv;
      ctxl[oidx] = (_Float16)(val - (float)hv);
    }
}

// ---------------- host ----------------
extern "C" void kernel_launch(void* const* d_in, const int* in_sizes, int n_in,
                              void* d_out, int out_size, void* d_ws, size_t ws_size,
                              hipStream_t stream)
{
  const float* x  = (const float*)d_in[0];
  const float* Wq = (const float*)d_in[1];
  const float* bq = (const float*)d_in[2];
  const float* Wk = (const float*)d_in[3];
  const float* bk = (const float*)d_in[4];
  const float* Wv = (const float*)d_in[5];
  const float* bv = (const float*)d_in[6];
  const float* Wo = (const float*)d_in[7];
  const float* bo = (const float*)d_in[8];
  float* out = (float*)d_out;
  char*  ws  = (char*)d_ws;

  const size_t MB = 1u << 20;
  _Float16* xh      = (_Float16*)(ws + 0*MB);
  _Float16* xl      = (_Float16*)(ws + 4*MB);
  _Float16* wplanes = (_Float16*)(ws + 8*MB);    // 8 x 2 MiB transposed W planes
  _Float16* Qh      = (_Float16*)(ws + 24*MB);
  _Float16* Ql      = (_Float16*)(ws + 28*MB);
  _Float16* Kh      = (_Float16*)(ws + 32*MB);
  _Float16* Kl      = (_Float16*)(ws + 36*MB);
  _Float16* VtH     = (_Float16*)(ws + 40*MB);   // [1024 dims][2048 rows]
  _Float16* VtL     = (_Float16*)(ws + 44*MB);
  _Float16* ctxh    = (_Float16*)(ws + 48*MB);
  _Float16* ctxl    = (_Float16*)(ws + 52*MB);
  const size_t base = 56*MB;
  unsigned* state = (unsigned*)(ws + base);
  float*    thr   = (float*)(ws + base + 4096);
  unsigned* ccnt  = (unsigned*)(ws + base + 8192);
  unsigned* ghist = (unsigned*)(ws + base + 16384);           // 1 MiB
  unsigned* cand  = (unsigned*)(ws + base + 16384 + 1048576); // 3 MiB

  split_x<<<2048, 256, 0, stream>>>(x, xh, xl);
  split_wT<<<dim3(16, 16, 4), 256, 0, stream>>>(Wq, Wk, Wv, Wo, wplanes);
  gemm_mfma_qkv<<<dim3(8, 16, 3), 256, 0, stream>>>(xh, xl, wplanes, bq, bk, bv,
                                                    Qh, Ql, Kh, Kl, VtH, VtL);

  init14<<<256, 256, 0, stream>>>(ghist, ccnt);
  scores_hist<<<dim3(16, 8, HH), 512, 0, stream>>>(Qh, Ql, Kh, Kl, ghist);
  scan14<<<HH, 256, 0, stream>>>(ghist, state);
  compact_recompute<<<dim3(16, 8, HH), 512, 0, stream>>>(Qh, Ql, Kh, Kl, state, cand, ccnt);
  final_select_list<<<HH, 256, 0, stream>>>(cand, ccnt, state, thr);
  flash_pv<<<dim3(32, HH), 256, 0, stream>>>(Qh, Ql, Kh, Kl, VtH, VtL, thr, ctxh, ctxl);

  gemm_mfma_o<<<dim3(8, 16), 256, 0, stream>>>(ctxh, ctxl, wplanes, bo, out);
}